// Round 1
// baseline (409.240 us; speedup 1.0000x reference)
//
#include <hip/hip_runtime.h>
#include <hip/hip_bf16.h>
#include <stdint.h>

typedef unsigned short u16;
typedef __attribute__((ext_vector_type(8))) short short8;
typedef __attribute__((ext_vector_type(4))) float f32x4;
typedef __attribute__((ext_vector_type(4))) u16 u16x4;

#define NB 2
#define NS 2048
#define ND 1024
#define NH 16
#define NM 4096   // NB*NS

// RNE f32 -> bf16 (self-contained, no header dependence)
__device__ __forceinline__ u16 f2bf(float f){
  union { float f; unsigned u; } v; v.f = f;
  unsigned r = v.u + 0x7fff + ((v.u >> 16) & 1);
  return (u16)(r >> 16);
}

__device__ __forceinline__ void gload_lds16(const u16* g, u16* l){
  __builtin_amdgcn_global_load_lds(
      (const __attribute__((address_space(1))) unsigned int*)g,
      (__attribute__((address_space(3))) unsigned int*)l, 16, 0, 0);
}

// ---------------- f32 -> bf16 convert ----------------
__global__ void cvt_kernel(const float* __restrict__ src, u16* __restrict__ dst, int n){
  int i = (blockIdx.x * blockDim.x + threadIdx.x) * 4;
  if (i < n){
    float4 v = *(const float4*)(src + i);
    u16x4 o = { f2bf(v.x), f2bf(v.y), f2bf(v.z), f2bf(v.w) };
    *(u16x4*)(dst + i) = o;
  }
}

// ---------------- NT GEMM core: C[128x128] = A[128xK] * W[128xK]^T ----------------
// LDS layout: [128 rows][64 cols] bf16, row = 128B, XOR-swizzle byte ^= ((row&7)<<4)
// applied as: linear global_load_lds dest + inverse-swizzled global source + swizzled ds_read.
__device__ __forceinline__ void gemm_core(
    const u16* __restrict__ A, const u16* __restrict__ W,
    int m0, int n0, u16* lsA, u16* lsB, f32x4 acc[4][4])
{
  const int tid = threadIdx.x;
  const int l   = tid & 63;
  const int wr  = (tid >> 7) & 1;      // wave row (2x2 wave grid)
  const int wc  = (tid >> 6) & 1;      // wave col
  const int lr  = l & 15;
  const int lkb = (l >> 4) << 4;       // k byte offset within 32-elem slice: 0,16,32,48
  const int sr  = tid >> 3;            // staging row block 0..31
  const int scb = (tid & 7) << 4;      // staging col byte 0..112

  for (int kt = 0; kt < 16; ++kt){
    const int k0 = kt << 6;
    #pragma unroll
    for (int i = 0; i < 4; ++i){
      int r   = (i << 5) + sr;
      int cbs = scb ^ ((r & 7) << 4);  // inverse-swizzled source chunk
      gload_lds16(&A[(size_t)(m0 + r) * ND + k0 + (cbs >> 1)], &lsA[r * 64 + (scb >> 1)]);
      gload_lds16(&W[(size_t)(n0 + r) * ND + k0 + (cbs >> 1)], &lsB[r * 64 + (scb >> 1)]);
    }
    __syncthreads();   // compiler drains vmcnt before s_barrier

    short8 af[4][2], bf[4][2];
    #pragma unroll
    for (int m16 = 0; m16 < 4; ++m16){
      int r  = (wr << 6) + (m16 << 4) + lr;
      int rx = (r & 7) << 4;
      #pragma unroll
      for (int ks = 0; ks < 2; ++ks){
        int off = r * 128 + (((ks << 6) + lkb) ^ rx);
        af[m16][ks] = *(const short8*)((const char*)lsA + off);
      }
    }
    #pragma unroll
    for (int n16 = 0; n16 < 4; ++n16){
      int r  = (wc << 6) + (n16 << 4) + lr;
      int rx = (r & 7) << 4;
      #pragma unroll
      for (int ks = 0; ks < 2; ++ks){
        int off = r * 128 + (((ks << 6) + lkb) ^ rx);
        bf[n16][ks] = *(const short8*)((const char*)lsB + off);
      }
    }
    #pragma unroll
    for (int m16 = 0; m16 < 4; ++m16)
      #pragma unroll
      for (int n16 = 0; n16 < 4; ++n16){
        acc[m16][n16] = __builtin_amdgcn_mfma_f32_16x16x32_bf16(af[m16][0], bf[n16][0], acc[m16][n16], 0, 0, 0);
        acc[m16][n16] = __builtin_amdgcn_mfma_f32_16x16x32_bf16(af[m16][1], bf[n16][1], acc[m16][n16], 0, 0, 0);
      }
    __syncthreads();
  }
}

// ---------------- fused QKV projection (grid.z selects W/output) ----------------
__global__ __launch_bounds__(256) void gemm_qkv(
    const u16* __restrict__ xb,
    const u16* __restrict__ Wqb, const u16* __restrict__ Wkb, const u16* __restrict__ Wvb,
    u16* __restrict__ Qo, u16* __restrict__ Ko, u16* __restrict__ Vt)
{
  __shared__ u16 lsA[128*64];
  __shared__ u16 lsB[128*64];
  const int z = blockIdx.z;
  const u16* W = (z == 0) ? Wqb : (z == 1) ? Wkb : Wvb;
  const int m0 = blockIdx.y << 7, n0 = blockIdx.x << 7;
  f32x4 acc[4][4] = {};
  gemm_core(xb, W, m0, n0, lsA, lsB, acc);

  const int l  = threadIdx.x & 63;
  const int wr = (threadIdx.x >> 7) & 1, wc = (threadIdx.x >> 6) & 1;
  const int rb = m0 + (wr << 6) + ((l >> 4) << 2);   // C row base (4 consecutive rows)
  const int cb = n0 + (wc << 6) + (l & 15);          // C col

  if (z < 2){
    u16* C = (z == 0) ? Qo : Ko;
    #pragma unroll
    for (int m16 = 0; m16 < 4; ++m16)
      #pragma unroll
      for (int n16 = 0; n16 < 4; ++n16)
        #pragma unroll
        for (int r = 0; r < 4; ++r)
          C[(size_t)(rb + (m16 << 4) + r) * ND + cb + (n16 << 4)] = f2bf(acc[m16][n16][r]);
  } else {
    // V transposed: Vt[((b*16+h)*64+hd)*2048 + s]; 4 rows (s) contiguous -> packed store
    #pragma unroll
    for (int m16 = 0; m16 < 4; ++m16){
      int srow = rb + (m16 << 4);
      int bi = srow >> 11, s = srow & 2047;
      #pragma unroll
      for (int n16 = 0; n16 < 4; ++n16){
        int col = cb + (n16 << 4);
        u16x4 pk = { f2bf(acc[m16][n16][0]), f2bf(acc[m16][n16][1]),
                     f2bf(acc[m16][n16][2]), f2bf(acc[m16][n16][3]) };
        *(u16x4*)&Vt[((size_t)(bi * 16 + (col >> 6)) * 64 + (col & 63)) * 2048 + s] = pk;
      }
    }
  }
}

// ---------------- output projection: out = ctx @ Wo^T + bo (f32) ----------------
__global__ __launch_bounds__(256) void gemm_out(
    const u16* __restrict__ ctxb, const u16* __restrict__ Wob,
    const float* __restrict__ bo, float* __restrict__ out)
{
  __shared__ u16 lsA[128*64];
  __shared__ u16 lsB[128*64];
  const int m0 = blockIdx.y << 7, n0 = blockIdx.x << 7;
  f32x4 acc[4][4] = {};
  gemm_core(ctxb, Wob, m0, n0, lsA, lsB, acc);

  const int l  = threadIdx.x & 63;
  const int wr = (threadIdx.x >> 7) & 1, wc = (threadIdx.x >> 6) & 1;
  const int rb = m0 + (wr << 6) + ((l >> 4) << 2);
  const int cb = n0 + (wc << 6) + (l & 15);
  #pragma unroll
  for (int m16 = 0; m16 < 4; ++m16)
    #pragma unroll
    for (int n16 = 0; n16 < 4; ++n16)
      #pragma unroll
      for (int r = 0; r < 4; ++r){
        int col = cb + (n16 << 4);
        out[(size_t)(rb + (m16 << 4) + r) * ND + col] = acc[m16][n16][r] + bo[col];
      }
}

// ---------------- causal flash attention ----------------
// grid (S/64, B*H), 256 thr = 4 waves; wave w owns q rows qi*64+w*16..+15.
// Q in regs; K fragments direct from global (NT form); V via pre-transposed Vt.
// P transposed through per-wave padded LDS (stride 72 elems = 144B, 16B aligned).
__global__ __launch_bounds__(256) void attn_kernel(
    const u16* __restrict__ Q, const u16* __restrict__ K,
    const u16* __restrict__ Vt, u16* __restrict__ ctx)
{
  __shared__ __align__(16) u16 Plds[4][16][72];
  const int qi = blockIdx.x;
  const int bh = blockIdx.y;
  const int b = bh >> 4, h = bh & 15;
  const int tid = threadIdx.x;
  const int l = tid & 63, w = tid >> 6;
  const int lr = l & 15, lg = l >> 4;
  const int lk = lg << 3;

  const u16* Qrow = &Q[(size_t)(b * NS + qi * 64 + w * 16 + lr) * ND + h * 64];
  short8 qf0 = *(const short8*)&Qrow[lk];
  short8 qf1 = *(const short8*)&Qrow[32 + lk];

  const u16* Kbp = &K[(size_t)(b * NS) * ND + h * 64];
  const u16* Vbp = &Vt[(size_t)bh * 64 * NS];

  float m_r[4], l_r[4];
  f32x4 acc_o[4] = {};
  #pragma unroll
  for (int r = 0; r < 4; ++r){ m_r[r] = -3e38f; l_r[r] = 0.f; }

  for (int t = 0; t <= qi; ++t){
    // ---- scores S = Q K^T / sqrt(D) ----
    f32x4 s[4];
    #pragma unroll
    for (int n16 = 0; n16 < 4; ++n16){
      const u16* kr = &Kbp[(size_t)(t * 64 + n16 * 16 + lr) * ND];
      short8 k0 = *(const short8*)&kr[lk];
      short8 k1 = *(const short8*)&kr[32 + lk];
      f32x4 z = {};
      z = __builtin_amdgcn_mfma_f32_16x16x32_bf16(qf0, k0, z, 0, 0, 0);
      z = __builtin_amdgcn_mfma_f32_16x16x32_bf16(qf1, k1, z, 0, 0, 0);
      s[n16] = z;
    }
    float pv[4][4];
    const bool diag = (t == qi);
    #pragma unroll
    for (int n16 = 0; n16 < 4; ++n16)
      #pragma unroll
      for (int r = 0; r < 4; ++r){
        float sv = s[n16][r] * 0.03125f;
        if (diag && (n16 * 16 + lr > w * 16 + lg * 4 + r)) sv = -3e38f;  // causal mask
        pv[n16][r] = sv;
      }
    // ---- online softmax (wave-parallel, 16-lane groups) ----
    float pm[4];
    #pragma unroll
    for (int r = 0; r < 4; ++r)
      pm[r] = fmaxf(fmaxf(pv[0][r], pv[1][r]), fmaxf(pv[2][r], pv[3][r]));
    #pragma unroll
    for (int off = 1; off < 16; off <<= 1)
      #pragma unroll
      for (int r = 0; r < 4; ++r)
        pm[r] = fmaxf(pm[r], __shfl_xor(pm[r], off));
    float esc[4], rs[4];
    #pragma unroll
    for (int r = 0; r < 4; ++r){
      float mn = fmaxf(m_r[r], pm[r]);
      esc[r] = __expf(m_r[r] - mn);
      m_r[r] = mn;
      rs[r] = 0.f;
    }
    #pragma unroll
    for (int n16 = 0; n16 < 4; ++n16)
      #pragma unroll
      for (int r = 0; r < 4; ++r){
        float p = __expf(pv[n16][r] - m_r[r]);
        pv[n16][r] = p;
        rs[r] += p;
      }
    #pragma unroll
    for (int off = 1; off < 16; off <<= 1)
      #pragma unroll
      for (int r = 0; r < 4; ++r)
        rs[r] += __shfl_xor(rs[r], off);
    #pragma unroll
    for (int r = 0; r < 4; ++r)
      l_r[r] = l_r[r] * esc[r] + rs[r];
    #pragma unroll
    for (int n16 = 0; n16 < 4; ++n16)
      #pragma unroll
      for (int r = 0; r < 4; ++r)
        acc_o[n16][r] *= esc[r];

    // ---- P -> bf16, transpose through LDS into A-fragment layout ----
    #pragma unroll
    for (int n16 = 0; n16 < 4; ++n16)
      #pragma unroll
      for (int r = 0; r < 4; ++r)
        Plds[w][lg * 4 + r][n16 * 16 + lr] = f2bf(pv[n16][r]);
    __syncthreads();
    short8 pa0 = *(const short8*)&Plds[w][lr][lk];
    short8 pa1 = *(const short8*)&Plds[w][lr][32 + lk];

    // ---- O += P V ----
    #pragma unroll
    for (int n16 = 0; n16 < 4; ++n16){
      const u16* vr = &Vbp[(size_t)(n16 * 16 + lr) * NS + t * 64];
      short8 v0 = *(const short8*)&vr[lk];
      short8 v1 = *(const short8*)&vr[32 + lk];
      acc_o[n16] = __builtin_amdgcn_mfma_f32_16x16x32_bf16(pa0, v0, acc_o[n16], 0, 0, 0);
      acc_o[n16] = __builtin_amdgcn_mfma_f32_16x16x32_bf16(pa1, v1, acc_o[n16], 0, 0, 0);
    }
    __syncthreads();
  }

  #pragma unroll
  for (int n16 = 0; n16 < 4; ++n16)
    #pragma unroll
    for (int r = 0; r < 4; ++r){
      float o = acc_o[n16][r] / l_r[r];
      int qg = qi * 64 + w * 16 + lg * 4 + r;
      ctx[(size_t)(b * NS + qg) * ND + h * 64 + n16 * 16 + lr] = f2bf(o);
    }
}

extern "C" void kernel_launch(void* const* d_in, const int* in_sizes, int n_in,
                              void* d_out, int out_size, void* d_ws, size_t ws_size,
                              hipStream_t stream)
{
  const float* x  = (const float*)d_in[0];
  const float* Wq = (const float*)d_in[1];
  const float* Wk = (const float*)d_in[2];
  const float* Wv = (const float*)d_in[3];
  const float* Wo = (const float*)d_in[4];
  const float* bo = (const float*)d_in[5];
  float* out = (float*)d_out;
  char* ws = (char*)d_ws;

  u16* xb  = (u16*)(ws);
  u16* Wqb = (u16*)(ws + (8u  << 20));
  u16* Wkb = (u16*)(ws + (10u << 20));
  u16* Wvb = (u16*)(ws + (12u << 20));
  u16* Wob = (u16*)(ws + (14u << 20));
  u16* Qb  = (u16*)(ws + (16u << 20));
  u16* Kb  = (u16*)(ws + (24u << 20));
  u16* Vtb = (u16*)(ws + (32u << 20));
  u16* Cb  = (u16*)(ws + (40u << 20));

  cvt_kernel<<<4096, 256, 0, stream>>>(x,  xb,  NM * ND);
  cvt_kernel<<<1024, 256, 0, stream>>>(Wq, Wqb, ND * ND);
  cvt_kernel<<<1024, 256, 0, stream>>>(Wk, Wkb, ND * ND);
  cvt_kernel<<<1024, 256, 0, stream>>>(Wv, Wvb, ND * ND);
  cvt_kernel<<<1024, 256, 0, stream>>>(Wo, Wob, ND * ND);

  gemm_qkv<<<dim3(8, 32, 3), 256, 0, stream>>>(xb, Wqb, Wkb, Wvb, Qb, Kb, Vtb);
  attn_kernel<<<dim3(32, 32), 256, 0, stream>>>(Qb, Kb, Vtb, Cb);
  gemm_out<<<dim3(8, 32), 256, 0, stream>>>(Cb, Wob, bo, out);
}

// Round 3
// 203.154 us; speedup vs baseline: 2.0144x; 2.0144x over previous
//
#include <hip/hip_runtime.h>
#include <hip/hip_bf16.h>
#include <stdint.h>

typedef unsigned short u16;
typedef __attribute__((ext_vector_type(8))) short short8;
typedef __attribute__((ext_vector_type(4))) float f32x4;
typedef __attribute__((ext_vector_type(4))) u16 u16x4;

#define NB 2
#define NS 2048
#define ND 1024
#define NH 16
#define NM 4096   // NB*NS

// RNE f32 -> bf16
__device__ __forceinline__ u16 f2bf(float f){
  union { float f; unsigned u; } v; v.f = f;
  unsigned r = v.u + 0x7fff + ((v.u >> 16) & 1);
  return (u16)(r >> 16);
}

__device__ __forceinline__ void gload_lds16(const u16* g, u16* l){
  __builtin_amdgcn_global_load_lds(
      (const __attribute__((address_space(1))) unsigned int*)g,
      (__attribute__((address_space(3))) unsigned int*)l, 16, 0, 0);
}

// DPP lane permute within 16-lane rows (macro so ctrl stays a literal constant)
#define DPPMOV(x, ctrl) __int_as_float(__builtin_amdgcn_update_dpp( \
    __float_as_int(x), __float_as_int(x), (ctrl), 0xF, 0xF, false))

__device__ __forceinline__ float row16_max(float x){
  x = fmaxf(x, DPPMOV(x, 0xB1));   // quad_perm xor1
  x = fmaxf(x, DPPMOV(x, 0x4E));   // quad_perm xor2
  x = fmaxf(x, DPPMOV(x, 0x141));  // row_half_mirror
  x = fmaxf(x, DPPMOV(x, 0x140));  // row_mirror
  return x;
}
__device__ __forceinline__ float row16_sum(float x){
  x += DPPMOV(x, 0xB1);
  x += DPPMOV(x, 0x4E);
  x += DPPMOV(x, 0x141);
  x += DPPMOV(x, 0x140);
  return x;
}

// ---------------- f32 -> bf16 convert ----------------
__global__ void cvt_kernel(const float* __restrict__ src, u16* __restrict__ dst, int n){
  int i = (blockIdx.x * blockDim.x + threadIdx.x) * 4;
  if (i < n){
    float4 v = *(const float4*)(src + i);
    u16x4 o = { f2bf(v.x), f2bf(v.y), f2bf(v.z), f2bf(v.w) };
    *(u16x4*)(dst + i) = o;
  }
}

// 4 weight matrices (1M elems each) in one launch: grid (1024, 4)
__global__ void cvt4_kernel(const float* __restrict__ a, const float* __restrict__ b,
                            const float* __restrict__ c, const float* __restrict__ d,
                            u16* __restrict__ oa, u16* __restrict__ ob,
                            u16* __restrict__ oc, u16* __restrict__ od){
  const float* s; u16* o;
  switch (blockIdx.y){
    case 0: s = a; o = oa; break;
    case 1: s = b; o = ob; break;
    case 2: s = c; o = oc; break;
    default: s = d; o = od; break;
  }
  int i = (blockIdx.x * blockDim.x + threadIdx.x) * 4;
  float4 v = *(const float4*)(s + i);
  u16x4 pk = { f2bf(v.x), f2bf(v.y), f2bf(v.z), f2bf(v.w) };
  *(u16x4*)(o + i) = pk;
}

// ---------------- NT GEMM core: C[128x128] = A[128xK] * W[128xK]^T ----------------
__device__ __forceinline__ void gemm_core(
    const u16* __restrict__ A, const u16* __restrict__ W,
    int m0, int n0, u16* lsA, u16* lsB, f32x4 acc[4][4])
{
  const int tid = threadIdx.x;
  const int l   = tid & 63;
  const int wr  = (tid >> 7) & 1;
  const int wc  = (tid >> 6) & 1;
  const int lr  = l & 15;
  const int lkb = (l >> 4) << 4;
  const int sr  = tid >> 3;
  const int scb = (tid & 7) << 4;

  for (int kt = 0; kt < 16; ++kt){
    const int k0 = kt << 6;
    #pragma unroll
    for (int i = 0; i < 4; ++i){
      int r   = (i << 5) + sr;
      int cbs = scb ^ ((r & 7) << 4);
      gload_lds16(&A[(size_t)(m0 + r) * ND + k0 + (cbs >> 1)], &lsA[r * 64 + (scb >> 1)]);
      gload_lds16(&W[(size_t)(n0 + r) * ND + k0 + (cbs >> 1)], &lsB[r * 64 + (scb >> 1)]);
    }
    __syncthreads();

    short8 af[4][2], bf[4][2];
    #pragma unroll
    for (int m16 = 0; m16 < 4; ++m16){
      int r  = (wr << 6) + (m16 << 4) + lr;
      int rx = (r & 7) << 4;
      #pragma unroll
      for (int ks = 0; ks < 2; ++ks){
        int off = r * 128 + (((ks << 6) + lkb) ^ rx);
        af[m16][ks] = *(const short8*)((const char*)lsA + off);
      }
    }
    #pragma unroll
    for (int n16 = 0; n16 < 4; ++n16){
      int r  = (wc << 6) + (n16 << 4) + lr;
      int rx = (r & 7) << 4;
      #pragma unroll
      for (int ks = 0; ks < 2; ++ks){
        int off = r * 128 + (((ks << 6) + lkb) ^ rx);
        bf[n16][ks] = *(const short8*)((const char*)lsB + off);
      }
    }
    #pragma unroll
    for (int m16 = 0; m16 < 4; ++m16)
      #pragma unroll
      for (int n16 = 0; n16 < 4; ++n16){
        acc[m16][n16] = __builtin_amdgcn_mfma_f32_16x16x32_bf16(af[m16][0], bf[n16][0], acc[m16][n16], 0, 0, 0);
        acc[m16][n16] = __builtin_amdgcn_mfma_f32_16x16x32_bf16(af[m16][1], bf[n16][1], acc[m16][n16], 0, 0, 0);
      }
    __syncthreads();
  }
}

// ---------------- fused QKV projection ----------------
__global__ __launch_bounds__(256) void gemm_qkv(
    const u16* __restrict__ xb,
    const u16* __restrict__ Wqb, const u16* __restrict__ Wkb, const u16* __restrict__ Wvb,
    u16* __restrict__ Qo, u16* __restrict__ Ko, u16* __restrict__ Vt)
{
  __shared__ u16 lsA[128*64];
  __shared__ u16 lsB[128*64];
  const int z = blockIdx.z;
  const u16* W = (z == 0) ? Wqb : (z == 1) ? Wkb : Wvb;
  const int m0 = blockIdx.y << 7, n0 = blockIdx.x << 7;
  f32x4 acc[4][4] = {};
  gemm_core(xb, W, m0, n0, lsA, lsB, acc);

  const int l  = threadIdx.x & 63;
  const int wr = (threadIdx.x >> 7) & 1, wc = (threadIdx.x >> 6) & 1;
  const int rb = m0 + (wr << 6) + ((l >> 4) << 2);
  const int cb = n0 + (wc << 6) + (l & 15);

  if (z < 2){
    u16* C = (z == 0) ? Qo : Ko;
    #pragma unroll
    for (int m16 = 0; m16 < 4; ++m16)
      #pragma unroll
      for (int n16 = 0; n16 < 4; ++n16)
        #pragma unroll
        for (int r = 0; r < 4; ++r)
          C[(size_t)(rb + (m16 << 4) + r) * ND + cb + (n16 << 4)] = f2bf(acc[m16][n16][r]);
  } else {
    #pragma unroll
    for (int m16 = 0; m16 < 4; ++m16){
      int srow = rb + (m16 << 4);
      int bi = srow >> 11, s = srow & 2047;
      #pragma unroll
      for (int n16 = 0; n16 < 4; ++n16){
        int col = cb + (n16 << 4);
        u16x4 pk = { f2bf(acc[m16][n16][0]), f2bf(acc[m16][n16][1]),
                     f2bf(acc[m16][n16][2]), f2bf(acc[m16][n16][3]) };
        *(u16x4*)&Vt[((size_t)(bi * 16 + (col >> 6)) * 64 + (col & 63)) * 2048 + s] = pk;
      }
    }
  }
}

// ---------------- output projection ----------------
__global__ __launch_bounds__(256) void gemm_out(
    const u16* __restrict__ ctxb, const u16* __restrict__ Wob,
    const float* __restrict__ bo, float* __restrict__ out)
{
  __shared__ u16 lsA[128*64];
  __shared__ u16 lsB[128*64];
  const int m0 = blockIdx.y << 7, n0 = blockIdx.x << 7;
  f32x4 acc[4][4] = {};
  gemm_core(ctxb, Wob, m0, n0, lsA, lsB, acc);

  const int l  = threadIdx.x & 63;
  const int wr = (threadIdx.x >> 7) & 1, wc = (threadIdx.x >> 6) & 1;
  const int rb = m0 + (wr << 6) + ((l >> 4) << 2);
  const int cb = n0 + (wc << 6) + (l & 15);
  #pragma unroll
  for (int m16 = 0; m16 < 4; ++m16)
    #pragma unroll
    for (int n16 = 0; n16 < 4; ++n16)
      #pragma unroll
      for (int r = 0; r < 4; ++r){
        int col = cb + (n16 << 4);
        out[(size_t)(rb + (m16 << 4) + r) * ND + col] = acc[m16][n16][r] + bo[col];
      }
}

// ---------------- causal flash attention, balanced barrier-free ----------------
// grid (16, B*H), 256 thr = 4 independent waves. Wave-job = blockIdx.x*4 + w
// handles 16-row q-tiles {job, 127-job} sequentially -> every wave does 33-34
// kv-iterations (perfect balance). No __syncthreads anywhere: the P transpose
// LDS buffer is wave-private; in-wave ordering via s_waitcnt lgkmcnt(0).
__global__ __launch_bounds__(256) void attn_kernel(
    const u16* __restrict__ Q, const u16* __restrict__ K,
    const u16* __restrict__ Vt, u16* __restrict__ ctx)
{
  __shared__ __align__(16) u16 Plds[4][16][72];
  const int bh = blockIdx.y;
  const int b = bh >> 4, h = bh & 15;
  const int tid = threadIdx.x;
  const int l = tid & 63, w = tid >> 6;
  const int lr = l & 15, lg = l >> 4;
  const int lk = lg << 3;
  const int job = blockIdx.x * 4 + w;   // 0..63

  const u16* Kbp = &K[(size_t)(b * NS) * ND + h * 64];
  const u16* Vbp = &Vt[(size_t)bh * 64 * NS];

  #pragma unroll 1
  for (int ti = 0; ti < 2; ++ti){
    const int tile = ti ? (127 - job) : job;
    const int tmax = tile >> 2;
    const int qloc = (tile & 3) << 4;   // tile's row offset within the 64-row kv block

    const u16* Qrow = &Q[(size_t)(b * NS + tile * 16 + lr) * ND + h * 64];
    short8 qf0 = *(const short8*)&Qrow[lk];
    short8 qf1 = *(const short8*)&Qrow[32 + lk];

    float m_r[4], l_r[4];
    f32x4 acc_o[4] = {};
    #pragma unroll
    for (int r = 0; r < 4; ++r){ m_r[r] = -3e38f; l_r[r] = 0.f; }

    for (int t = 0; t <= tmax; ++t){
      // K fragments
      short8 kf[4][2];
      #pragma unroll
      for (int n16 = 0; n16 < 4; ++n16){
        const u16* kr = &Kbp[(size_t)(t * 64 + n16 * 16 + lr) * ND];
        kf[n16][0] = *(const short8*)&kr[lk];
        kf[n16][1] = *(const short8*)&kr[32 + lk];
      }
      // V fragments: issue early, consume after softmax
      short8 vf[4][2];
      #pragma unroll
      for (int n16 = 0; n16 < 4; ++n16){
        const u16* vr = &Vbp[(size_t)(n16 * 16 + lr) * NS + t * 64];
        vf[n16][0] = *(const short8*)&vr[lk];
        vf[n16][1] = *(const short8*)&vr[32 + lk];
      }
      // S = Q K^T
      f32x4 s[4];
      #pragma unroll
      for (int n16 = 0; n16 < 4; ++n16){
        f32x4 z = {};
        z = __builtin_amdgcn_mfma_f32_16x16x32_bf16(qf0, kf[n16][0], z, 0, 0, 0);
        z = __builtin_amdgcn_mfma_f32_16x16x32_bf16(qf1, kf[n16][1], z, 0, 0, 0);
        s[n16] = z;
      }
      float pv[4][4];
      const bool diag = (t == tmax);
      #pragma unroll
      for (int n16 = 0; n16 < 4; ++n16)
        #pragma unroll
        for (int r = 0; r < 4; ++r){
          float sv = s[n16][r] * 0.03125f;
          if (diag && (n16 * 16 + lr > qloc + lg * 4 + r)) sv = -3e38f;
          pv[n16][r] = sv;
        }
      // online softmax: DPP reduce across the 16 lanes of each row-group
      float esc[4], rs[4];
      #pragma unroll
      for (int r = 0; r < 4; ++r){
        float pm = fmaxf(fmaxf(pv[0][r], pv[1][r]), fmaxf(pv[2][r], pv[3][r]));
        pm = row16_max(pm);
        float mn = fmaxf(m_r[r], pm);
        esc[r] = __expf(m_r[r] - mn);
        m_r[r] = mn;
      }
      #pragma unroll
      for (int n16 = 0; n16 < 4; ++n16)
        #pragma unroll
        for (int r = 0; r < 4; ++r)
          pv[n16][r] = __expf(pv[n16][r] - m_r[r]);
      #pragma unroll
      for (int r = 0; r < 4; ++r){
        float t0 = (pv[0][r] + pv[1][r]) + (pv[2][r] + pv[3][r]);
        rs[r] = row16_sum(t0);
        l_r[r] = l_r[r] * esc[r] + rs[r];
      }
      #pragma unroll
      for (int n16 = 0; n16 < 4; ++n16)
        #pragma unroll
        for (int r = 0; r < 4; ++r)
          acc_o[n16][r] *= esc[r];

      // P -> bf16, transpose through wave-private LDS
      #pragma unroll
      for (int n16 = 0; n16 < 4; ++n16)
        #pragma unroll
        for (int r = 0; r < 4; ++r)
          Plds[w][lg * 4 + r][n16 * 16 + lr] = f2bf(pv[n16][r]);
      asm volatile("s_waitcnt lgkmcnt(0)" ::: "memory");
      __builtin_amdgcn_sched_barrier(0);
      short8 pa0 = *(const short8*)&Plds[w][lr][lk];
      short8 pa1 = *(const short8*)&Plds[w][lr][32 + lk];

      // O += P V
      #pragma unroll
      for (int n16 = 0; n16 < 4; ++n16){
        acc_o[n16] = __builtin_amdgcn_mfma_f32_16x16x32_bf16(pa0, vf[n16][0], acc_o[n16], 0, 0, 0);
        acc_o[n16] = __builtin_amdgcn_mfma_f32_16x16x32_bf16(pa1, vf[n16][1], acc_o[n16], 0, 0, 0);
      }
    }

    #pragma unroll
    for (int n16 = 0; n16 < 4; ++n16)
      #pragma unroll
      for (int r = 0; r < 4; ++r){
        float o = acc_o[n16][r] / l_r[r];
        int qg = tile * 16 + lg * 4 + r;
        ctx[(size_t)(b * NS + qg) * ND + h * 64 + n16 * 16 + lr] = f2bf(o);
      }
  }
}

extern "C" void kernel_launch(void* const* d_in, const int* in_sizes, int n_in,
                              void* d_out, int out_size, void* d_ws, size_t ws_size,
                              hipStream_t stream)
{
  const float* x  = (const float*)d_in[0];
  const float* Wq = (const float*)d_in[1];
  const float* Wk = (const float*)d_in[2];
  const float* Wv = (const float*)d_in[3];
  const float* Wo = (const float*)d_in[4];
  const float* bo = (const float*)d_in[5];
  float* out = (float*)d_out;
  char* ws = (char*)d_ws;

  u16* xb  = (u16*)(ws);
  u16* Wqb = (u16*)(ws + (8u  << 20));
  u16* Wkb = (u16*)(ws + (10u << 20));
  u16* Wvb = (u16*)(ws + (12u << 20));
  u16* Wob = (u16*)(ws + (14u << 20));
  u16* Qb  = (u16*)(ws + (16u << 20));
  u16* Kb  = (u16*)(ws + (24u << 20));
  u16* Vtb = (u16*)(ws + (32u << 20));
  u16* Cb  = (u16*)(ws + (40u << 20));

  cvt_kernel<<<4096, 256, 0, stream>>>(x, xb, NM * ND);
  cvt4_kernel<<<dim3(1024, 4), 256, 0, stream>>>(Wq, Wk, Wv, Wo, Wqb, Wkb, Wvb, Wob);

  gemm_qkv<<<dim3(8, 32, 3), 256, 0, stream>>>(xb, Wqb, Wkb, Wvb, Qb, Kb, Vtb);
  attn_kernel<<<dim3(16, 32), 256, 0, stream>>>(Qb, Kb, Vtb, Cb);
  gemm_out<<<dim3(8, 32), 256, 0, stream>>>(Cb, Wob, bo, out);
}

// Round 4
// 148.114 us; speedup vs baseline: 2.7630x; 1.3716x over previous
//
#include <hip/hip_runtime.h>
#include <hip/hip_bf16.h>
#include <stdint.h>

typedef unsigned short u16;
typedef __attribute__((ext_vector_type(8))) short short8;
typedef __attribute__((ext_vector_type(4))) float f32x4;
typedef __attribute__((ext_vector_type(4))) u16 u16x4;

#define NB 2
#define NS 2048
#define ND 1024
#define NH 16
#define NM 4096   // NB*NS

// RNE f32 -> bf16
__device__ __forceinline__ u16 f2bf(float f){
  union { float f; unsigned u; } v; v.f = f;
  unsigned r = v.u + 0x7fff + ((v.u >> 16) & 1);
  return (u16)(r >> 16);
}

__device__ __forceinline__ void gload_lds16(const u16* g, u16* l){
  __builtin_amdgcn_global_load_lds(
      (const __attribute__((address_space(1))) unsigned int*)g,
      (__attribute__((address_space(3))) unsigned int*)l, 16, 0, 0);
}

// DPP lane permute within 16-lane rows (macro keeps ctrl a literal constant)
#define DPPMOV(x, ctrl) __int_as_float(__builtin_amdgcn_update_dpp( \
    __float_as_int(x), __float_as_int(x), (ctrl), 0xF, 0xF, false))

__device__ __forceinline__ float row16_max(float x){
  x = fmaxf(x, DPPMOV(x, 0xB1));   // quad_perm xor1
  x = fmaxf(x, DPPMOV(x, 0x4E));   // quad_perm xor2
  x = fmaxf(x, DPPMOV(x, 0x141));  // row_half_mirror
  x = fmaxf(x, DPPMOV(x, 0x140));  // row_mirror
  return x;
}
__device__ __forceinline__ float row16_sum(float x){
  x += DPPMOV(x, 0xB1);
  x += DPPMOV(x, 0x4E);
  x += DPPMOV(x, 0x141);
  x += DPPMOV(x, 0x140);
  return x;
}

// ---------------- f32 -> bf16 convert ----------------
__global__ void cvt_kernel(const float* __restrict__ src, u16* __restrict__ dst, int n){
  int i = (blockIdx.x * blockDim.x + threadIdx.x) * 4;
  if (i < n){
    float4 v = *(const float4*)(src + i);
    u16x4 o = { f2bf(v.x), f2bf(v.y), f2bf(v.z), f2bf(v.w) };
    *(u16x4*)(dst + i) = o;
  }
}

__global__ void cvt4_kernel(const float* __restrict__ a, const float* __restrict__ b,
                            const float* __restrict__ c, const float* __restrict__ d,
                            u16* __restrict__ oa, u16* __restrict__ ob,
                            u16* __restrict__ oc, u16* __restrict__ od){
  const float* s; u16* o;
  switch (blockIdx.y){
    case 0: s = a; o = oa; break;
    case 1: s = b; o = ob; break;
    case 2: s = c; o = oc; break;
    default: s = d; o = od; break;
  }
  int i = (blockIdx.x * blockDim.x + threadIdx.x) * 4;
  float4 v = *(const float4*)(s + i);
  u16x4 pk = { f2bf(v.x), f2bf(v.y), f2bf(v.z), f2bf(v.w) };
  *(u16x4*)(o + i) = pk;
}

// ---------------- NT GEMM core (unchanged) ----------------
__device__ __forceinline__ void gemm_core(
    const u16* __restrict__ A, const u16* __restrict__ W,
    int m0, int n0, u16* lsA, u16* lsB, f32x4 acc[4][4])
{
  const int tid = threadIdx.x;
  const int l   = tid & 63;
  const int wr  = (tid >> 7) & 1;
  const int wc  = (tid >> 6) & 1;
  const int lr  = l & 15;
  const int lkb = (l >> 4) << 4;
  const int sr  = tid >> 3;
  const int scb = (tid & 7) << 4;

  for (int kt = 0; kt < 16; ++kt){
    const int k0 = kt << 6;
    #pragma unroll
    for (int i = 0; i < 4; ++i){
      int r   = (i << 5) + sr;
      int cbs = scb ^ ((r & 7) << 4);
      gload_lds16(&A[(size_t)(m0 + r) * ND + k0 + (cbs >> 1)], &lsA[r * 64 + (scb >> 1)]);
      gload_lds16(&W[(size_t)(n0 + r) * ND + k0 + (cbs >> 1)], &lsB[r * 64 + (scb >> 1)]);
    }
    __syncthreads();

    short8 af[4][2], bf[4][2];
    #pragma unroll
    for (int m16 = 0; m16 < 4; ++m16){
      int r  = (wr << 6) + (m16 << 4) + lr;
      int rx = (r & 7) << 4;
      #pragma unroll
      for (int ks = 0; ks < 2; ++ks){
        int off = r * 128 + (((ks << 6) + lkb) ^ rx);
        af[m16][ks] = *(const short8*)((const char*)lsA + off);
      }
    }
    #pragma unroll
    for (int n16 = 0; n16 < 4; ++n16){
      int r  = (wc << 6) + (n16 << 4) + lr;
      int rx = (r & 7) << 4;
      #pragma unroll
      for (int ks = 0; ks < 2; ++ks){
        int off = r * 128 + (((ks << 6) + lkb) ^ rx);
        bf[n16][ks] = *(const short8*)((const char*)lsB + off);
      }
    }
    #pragma unroll
    for (int m16 = 0; m16 < 4; ++m16)
      #pragma unroll
      for (int n16 = 0; n16 < 4; ++n16){
        acc[m16][n16] = __builtin_amdgcn_mfma_f32_16x16x32_bf16(af[m16][0], bf[n16][0], acc[m16][n16], 0, 0, 0);
        acc[m16][n16] = __builtin_amdgcn_mfma_f32_16x16x32_bf16(af[m16][1], bf[n16][1], acc[m16][n16], 0, 0, 0);
      }
    __syncthreads();
  }
}

// ---------------- fused QKV projection ----------------
__global__ __launch_bounds__(256) void gemm_qkv(
    const u16* __restrict__ xb,
    const u16* __restrict__ Wqb, const u16* __restrict__ Wkb, const u16* __restrict__ Wvb,
    u16* __restrict__ Qo, u16* __restrict__ Ko, u16* __restrict__ Vt)
{
  __shared__ u16 lsA[128*64];
  __shared__ u16 lsB[128*64];
  const int z = blockIdx.z;
  const u16* W = (z == 0) ? Wqb : (z == 1) ? Wkb : Wvb;
  const int m0 = blockIdx.y << 7, n0 = blockIdx.x << 7;
  f32x4 acc[4][4] = {};
  gemm_core(xb, W, m0, n0, lsA, lsB, acc);

  const int l  = threadIdx.x & 63;
  const int wr = (threadIdx.x >> 7) & 1, wc = (threadIdx.x >> 6) & 1;
  const int rb = m0 + (wr << 6) + ((l >> 4) << 2);
  const int cb = n0 + (wc << 6) + (l & 15);

  if (z < 2){
    u16* C = (z == 0) ? Qo : Ko;
    #pragma unroll
    for (int m16 = 0; m16 < 4; ++m16)
      #pragma unroll
      for (int n16 = 0; n16 < 4; ++n16)
        #pragma unroll
        for (int r = 0; r < 4; ++r)
          C[(size_t)(rb + (m16 << 4) + r) * ND + cb + (n16 << 4)] = f2bf(acc[m16][n16][r]);
  } else {
    #pragma unroll
    for (int m16 = 0; m16 < 4; ++m16){
      int srow = rb + (m16 << 4);
      int bi = srow >> 11, s = srow & 2047;
      #pragma unroll
      for (int n16 = 0; n16 < 4; ++n16){
        int col = cb + (n16 << 4);
        u16x4 pk = { f2bf(acc[m16][n16][0]), f2bf(acc[m16][n16][1]),
                     f2bf(acc[m16][n16][2]), f2bf(acc[m16][n16][3]) };
        *(u16x4*)&Vt[((size_t)(bi * 16 + (col >> 6)) * 64 + (col & 63)) * 2048 + s] = pk;
      }
    }
  }
}

// ---------------- output projection ----------------
__global__ __launch_bounds__(256) void gemm_out(
    const u16* __restrict__ ctxb, const u16* __restrict__ Wob,
    const float* __restrict__ bo, float* __restrict__ out)
{
  __shared__ u16 lsA[128*64];
  __shared__ u16 lsB[128*64];
  const int m0 = blockIdx.y << 7, n0 = blockIdx.x << 7;
  f32x4 acc[4][4] = {};
  gemm_core(ctxb, Wob, m0, n0, lsA, lsB, acc);

  const int l  = threadIdx.x & 63;
  const int wr = (threadIdx.x >> 7) & 1, wc = (threadIdx.x >> 6) & 1;
  const int rb = m0 + (wr << 6) + ((l >> 4) << 2);
  const int cb = n0 + (wc << 6) + (l & 15);
  #pragma unroll
  for (int m16 = 0; m16 < 4; ++m16)
    #pragma unroll
    for (int n16 = 0; n16 < 4; ++n16)
      #pragma unroll
      for (int r = 0; r < 4; ++r){
        int col = cb + (n16 << 4);
        out[(size_t)(rb + (m16 << 4) + r) * ND + col] = acc[m16][n16][r] + bo[col];
      }
}

// ---------------- causal flash attention, block-cooperative LDS staging ----------------
// grid (16, B*H), 256 thr = 4 waves. Block p handles 64-row q-supertiles {p, 31-p}
// sequentially (33 kv-iterations total -> all 512 blocks balanced). Per iteration the
// block stages the shared 64x64 K and V tiles into double-buffered swizzled LDS via
// global_load_lds (prefetch-next-then-compute, 1 barrier/iter). Wave w owns q rows
// st*64 + w*16 .. +15; softmax rows are wave-private (DPP reduce, no cross-wave).
// stage: rows stride srcStride elems; chunk XOR-swizzle on the GLOBAL side, linear LDS dest.
__device__ __forceinline__ void stage_tile(const u16* src, int srcStride, u16* lds, int tid){
  const int rl = tid >> 3;                 // row 0..31
  const int ch = tid & 7;                  // 16B chunk within 128B row
  const int cs = ch ^ (rl & 7);            // inverse-swizzled source chunk
  gload_lds16(&src[(size_t)rl * srcStride + cs * 8],        &lds[rl * 64 + ch * 8]);
  gload_lds16(&src[(size_t)(rl + 32) * srcStride + cs * 8], &lds[(rl + 32) * 64 + ch * 8]);
}

__global__ __launch_bounds__(256) void attn_kernel(
    const u16* __restrict__ Q, const u16* __restrict__ K,
    const u16* __restrict__ Vt, u16* __restrict__ ctx)
{
  __shared__ __align__(16) u16 lsK[2][64*64];
  __shared__ __align__(16) u16 lsV[2][64*64];
  __shared__ __align__(16) u16 Plds[4][16][72];
  const int bh = blockIdx.y;
  const int b = bh >> 4, h = bh & 15;
  const int tid = threadIdx.x;
  const int l = tid & 63, w = tid >> 6;
  const int lr = l & 15, lg = l >> 4;
  const int lkB = lg << 4;                 // byte offset of this lane-group's 16B k-slice
  const int qloc = w << 4;                 // wave's row offset within the 64-row supertile

  const u16* Kb0 = &K[(size_t)(b * NS) * ND + h * 64];
  const u16* Vb0 = &Vt[(size_t)bh * 64 * NS];

  #pragma unroll 1
  for (int ph = 0; ph < 2; ++ph){
    const int st = ph ? (31 - blockIdx.x) : blockIdx.x;

    const u16* Qrow = &Q[(size_t)(b * NS + st * 64 + qloc + lr) * ND + h * 64];
    short8 qf0 = *(const short8*)&Qrow[lg * 8];
    short8 qf1 = *(const short8*)&Qrow[32 + lg * 8];

    float m_r[4], l_r[4];
    f32x4 acc_o[4] = {};
    #pragma unroll
    for (int r = 0; r < 4; ++r){ m_r[r] = -3e38f; l_r[r] = 0.f; }

    int cur = 0;
    stage_tile(Kb0, ND, &lsK[0][0], tid);
    stage_tile(Vb0, NS, &lsV[0][0], tid);
    __syncthreads();

    #pragma unroll 1
    for (int t = 0; t <= st; ++t){
      if (t < st){
        stage_tile(&Kb0[(size_t)(t + 1) * 64 * ND], ND, &lsK[cur ^ 1][0], tid);
        stage_tile(&Vb0[(t + 1) * 64],              NS, &lsV[cur ^ 1][0], tid);
      }
      const char* Kc = (const char*)&lsK[cur][0];
      const char* Vc = (const char*)&lsV[cur][0];

      short8 kf[4][2], vf[4][2];
      #pragma unroll
      for (int n16 = 0; n16 < 4; ++n16){
        int r  = (n16 << 4) + lr;
        int rx = (r & 7) << 4;
        kf[n16][0] = *(const short8*)(Kc + r * 128 + (lkB ^ rx));
        kf[n16][1] = *(const short8*)(Kc + r * 128 + ((64 + lkB) ^ rx));
        vf[n16][0] = *(const short8*)(Vc + r * 128 + (lkB ^ rx));
        vf[n16][1] = *(const short8*)(Vc + r * 128 + ((64 + lkB) ^ rx));
      }

      // S = Q K^T
      f32x4 s[4];
      #pragma unroll
      for (int n16 = 0; n16 < 4; ++n16){
        f32x4 z = {};
        z = __builtin_amdgcn_mfma_f32_16x16x32_bf16(qf0, kf[n16][0], z, 0, 0, 0);
        z = __builtin_amdgcn_mfma_f32_16x16x32_bf16(qf1, kf[n16][1], z, 0, 0, 0);
        s[n16] = z;
      }
      float pv[4][4];
      const bool diag = (t == st);
      #pragma unroll
      for (int n16 = 0; n16 < 4; ++n16)
        #pragma unroll
        for (int r = 0; r < 4; ++r){
          float sv = s[n16][r] * 0.03125f;
          if (diag && (n16 * 16 + lr > qloc + lg * 4 + r)) sv = -3e38f;
          pv[n16][r] = sv;
        }
      // online softmax (16-lane DPP reduce; rows are wave-private)
      float esc[4];
      #pragma unroll
      for (int r = 0; r < 4; ++r){
        float pm = fmaxf(fmaxf(pv[0][r], pv[1][r]), fmaxf(pv[2][r], pv[3][r]));
        pm = row16_max(pm);
        float mn = fmaxf(m_r[r], pm);
        esc[r] = __expf(m_r[r] - mn);
        m_r[r] = mn;
      }
      #pragma unroll
      for (int n16 = 0; n16 < 4; ++n16)
        #pragma unroll
        for (int r = 0; r < 4; ++r)
          pv[n16][r] = __expf(pv[n16][r] - m_r[r]);
      #pragma unroll
      for (int r = 0; r < 4; ++r){
        float t0 = (pv[0][r] + pv[1][r]) + (pv[2][r] + pv[3][r]);
        l_r[r] = l_r[r] * esc[r] + row16_sum(t0);
      }
      #pragma unroll
      for (int n16 = 0; n16 < 4; ++n16)
        #pragma unroll
        for (int r = 0; r < 4; ++r)
          acc_o[n16][r] *= esc[r];

      // P -> bf16, transpose through wave-private LDS
      #pragma unroll
      for (int n16 = 0; n16 < 4; ++n16)
        #pragma unroll
        for (int r = 0; r < 4; ++r)
          Plds[w][lg * 4 + r][n16 * 16 + lr] = f2bf(pv[n16][r]);
      asm volatile("s_waitcnt lgkmcnt(0)" ::: "memory");
      __builtin_amdgcn_sched_barrier(0);
      short8 pa0 = *(const short8*)&Plds[w][lr][lg * 8];
      short8 pa1 = *(const short8*)&Plds[w][lr][32 + lg * 8];

      // O += P V
      #pragma unroll
      for (int n16 = 0; n16 < 4; ++n16){
        acc_o[n16] = __builtin_amdgcn_mfma_f32_16x16x32_bf16(pa0, vf[n16][0], acc_o[n16], 0, 0, 0);
        acc_o[n16] = __builtin_amdgcn_mfma_f32_16x16x32_bf16(pa1, vf[n16][1], acc_o[n16], 0, 0, 0);
      }
      __syncthreads();
      cur ^= 1;
    }

    #pragma unroll
    for (int n16 = 0; n16 < 4; ++n16)
      #pragma unroll
      for (int r = 0; r < 4; ++r){
        float o = acc_o[n16][r] / l_r[r];
        int qg = st * 64 + qloc + lg * 4 + r;
        ctx[(size_t)(b * NS + qg) * ND + h * 64 + n16 * 16 + lr] = f2bf(o);
      }
  }
}

extern "C" void kernel_launch(void* const* d_in, const int* in_sizes, int n_in,
                              void* d_out, int out_size, void* d_ws, size_t ws_size,
                              hipStream_t stream)
{
  const float* x  = (const float*)d_in[0];
  const float* Wq = (const float*)d_in[1];
  const float* Wk = (const float*)d_in[2];
  const float* Wv = (const float*)d_in[3];
  const float* Wo = (const float*)d_in[4];
  const float* bo = (const float*)d_in[5];
  float* out = (float*)d_out;
  char* ws = (char*)d_ws;

  u16* xb  = (u16*)(ws);
  u16* Wqb = (u16*)(ws + (8u  << 20));
  u16* Wkb = (u16*)(ws + (10u << 20));
  u16* Wvb = (u16*)(ws + (12u << 20));
  u16* Wob = (u16*)(ws + (14u << 20));
  u16* Qb  = (u16*)(ws + (16u << 20));
  u16* Kb  = (u16*)(ws + (24u << 20));
  u16* Vtb = (u16*)(ws + (32u << 20));
  u16* Cb  = (u16*)(ws + (40u << 20));

  cvt_kernel<<<4096, 256, 0, stream>>>(x, xb, NM * ND);
  cvt4_kernel<<<dim3(1024, 4), 256, 0, stream>>>(Wq, Wk, Wv, Wo, Wqb, Wkb, Wvb, Wob);

  gemm_qkv<<<dim3(8, 32, 3), 256, 0, stream>>>(xb, Wqb, Wkb, Wvb, Qb, Kb, Vtb);
  attn_kernel<<<dim3(16, 32), 256, 0, stream>>>(Qb, Kb, Vtb, Cb);
  gemm_out<<<dim3(8, 32), 256, 0, stream>>>(Cb, Wob, bo, out);
}

// Round 5
// 140.446 us; speedup vs baseline: 2.9139x; 1.0546x over previous
//
#include <hip/hip_runtime.h>
#include <hip/hip_bf16.h>
#include <stdint.h>

typedef unsigned short u16;
typedef __attribute__((ext_vector_type(8))) short short8;
typedef __attribute__((ext_vector_type(4))) float f32x4;
typedef __attribute__((ext_vector_type(4))) u16 u16x4;

#define NB 2
#define NS 2048
#define ND 1024
#define NH 16
#define NM 4096   // NB*NS

// 1/sqrt(1024) * log2(e): folded into Q so QK^T scores are base-2 scores
#define QSCALE 0.045084220f

#if __has_builtin(__builtin_amdgcn_exp2f)
#define EXP2(x) __builtin_amdgcn_exp2f(x)
#else
#define EXP2(x) exp2f(x)
#endif
#if __has_builtin(__builtin_amdgcn_rcpf)
#define RCP(x) __builtin_amdgcn_rcpf(x)
#else
#define RCP(x) (1.0f / (x))
#endif

// RNE f32 -> bf16
__device__ __forceinline__ u16 f2bf(float f){
  union { float f; unsigned u; } v; v.f = f;
  unsigned r = v.u + 0x7fff + ((v.u >> 16) & 1);
  return (u16)(r >> 16);
}

// packed f32 pair -> 2x bf16 in one u32 (hardware RNE)
__device__ __forceinline__ unsigned cvtpk(float lo, float hi){
  unsigned r;
  asm("v_cvt_pk_bf16_f32 %0, %1, %2" : "=v"(r) : "v"(lo), "v"(hi));
  return r;
}
__device__ __forceinline__ short8 pack8(f32x4 a, f32x4 b){
  union { unsigned u[4]; short8 s; } o;
  o.u[0] = cvtpk(a[0], a[1]);
  o.u[1] = cvtpk(a[2], a[3]);
  o.u[2] = cvtpk(b[0], b[1]);
  o.u[3] = cvtpk(b[2], b[3]);
  return o.s;
}

__device__ __forceinline__ void gload_lds16(const u16* g, u16* l){
  __builtin_amdgcn_global_load_lds(
      (const __attribute__((address_space(1))) unsigned int*)g,
      (__attribute__((address_space(3))) unsigned int*)l, 16, 0, 0);
}

// DPP lane permute within 16-lane rows
#define DPPMOV(x, ctrl) __int_as_float(__builtin_amdgcn_update_dpp( \
    __float_as_int(x), __float_as_int(x), (ctrl), 0xF, 0xF, false))

__device__ __forceinline__ float row16_max(float x){
  x = fmaxf(x, DPPMOV(x, 0xB1));   // quad_perm xor1
  x = fmaxf(x, DPPMOV(x, 0x4E));   // quad_perm xor2
  x = fmaxf(x, DPPMOV(x, 0x141));  // row_half_mirror
  x = fmaxf(x, DPPMOV(x, 0x140));  // row_mirror
  return x;
}
__device__ __forceinline__ float row16_sum(float x){
  x += DPPMOV(x, 0xB1);
  x += DPPMOV(x, 0x4E);
  x += DPPMOV(x, 0x141);
  x += DPPMOV(x, 0x140);
  return x;
}

// ---------------- f32 -> bf16 convert ----------------
__global__ void cvt_kernel(const float* __restrict__ src, u16* __restrict__ dst, int n){
  int i = (blockIdx.x * blockDim.x + threadIdx.x) * 4;
  if (i < n){
    float4 v = *(const float4*)(src + i);
    u16x4 o = { f2bf(v.x), f2bf(v.y), f2bf(v.z), f2bf(v.w) };
    *(u16x4*)(dst + i) = o;
  }
}

__global__ void cvt4_kernel(const float* __restrict__ a, const float* __restrict__ b,
                            const float* __restrict__ c, const float* __restrict__ d,
                            u16* __restrict__ oa, u16* __restrict__ ob,
                            u16* __restrict__ oc, u16* __restrict__ od){
  const float* s; u16* o;
  switch (blockIdx.y){
    case 0: s = a; o = oa; break;
    case 1: s = b; o = ob; break;
    case 2: s = c; o = oc; break;
    default: s = d; o = od; break;
  }
  int i = (blockIdx.x * blockDim.x + threadIdx.x) * 4;
  float4 v = *(const float4*)(s + i);
  u16x4 pk = { f2bf(v.x), f2bf(v.y), f2bf(v.z), f2bf(v.w) };
  *(u16x4*)(o + i) = pk;
}

// ---------------- NT GEMM core ----------------
__device__ __forceinline__ void gemm_core(
    const u16* __restrict__ A, const u16* __restrict__ W,
    int m0, int n0, u16* lsA, u16* lsB, f32x4 acc[4][4])
{
  const int tid = threadIdx.x;
  const int l   = tid & 63;
  const int wr  = (tid >> 7) & 1;
  const int wc  = (tid >> 6) & 1;
  const int lr  = l & 15;
  const int lkb = (l >> 4) << 4;
  const int sr  = tid >> 3;
  const int scb = (tid & 7) << 4;

  for (int kt = 0; kt < 16; ++kt){
    const int k0 = kt << 6;
    #pragma unroll
    for (int i = 0; i < 4; ++i){
      int r   = (i << 5) + sr;
      int cbs = scb ^ ((r & 7) << 4);
      gload_lds16(&A[(size_t)(m0 + r) * ND + k0 + (cbs >> 1)], &lsA[r * 64 + (scb >> 1)]);
      gload_lds16(&W[(size_t)(n0 + r) * ND + k0 + (cbs >> 1)], &lsB[r * 64 + (scb >> 1)]);
    }
    __syncthreads();

    short8 af[4][2], bf[4][2];
    #pragma unroll
    for (int m16 = 0; m16 < 4; ++m16){
      int r  = (wr << 6) + (m16 << 4) + lr;
      int rx = (r & 7) << 4;
      #pragma unroll
      for (int ks = 0; ks < 2; ++ks){
        int off = r * 128 + (((ks << 6) + lkb) ^ rx);
        af[m16][ks] = *(const short8*)((const char*)lsA + off);
      }
    }
    #pragma unroll
    for (int n16 = 0; n16 < 4; ++n16){
      int r  = (wc << 6) + (n16 << 4) + lr;
      int rx = (r & 7) << 4;
      #pragma unroll
      for (int ks = 0; ks < 2; ++ks){
        int off = r * 128 + (((ks << 6) + lkb) ^ rx);
        bf[n16][ks] = *(const short8*)((const char*)lsB + off);
      }
    }
    #pragma unroll
    for (int m16 = 0; m16 < 4; ++m16)
      #pragma unroll
      for (int n16 = 0; n16 < 4; ++n16){
        acc[m16][n16] = __builtin_amdgcn_mfma_f32_16x16x32_bf16(af[m16][0], bf[n16][0], acc[m16][n16], 0, 0, 0);
        acc[m16][n16] = __builtin_amdgcn_mfma_f32_16x16x32_bf16(af[m16][1], bf[n16][1], acc[m16][n16], 0, 0, 0);
      }
    __syncthreads();
  }
}

// ---------------- fused QKV projection: grid (32, 8, 3), x = m-row ----------------
__global__ __launch_bounds__(256) void gemm_qkv(
    const u16* __restrict__ xb,
    const u16* __restrict__ Wqb, const u16* __restrict__ Wkb, const u16* __restrict__ Wvb,
    u16* __restrict__ Qo, u16* __restrict__ Ko, u16* __restrict__ Vt)
{
  __shared__ u16 lsA[128*64];
  __shared__ u16 lsB[128*64];
  const int z = blockIdx.z;
  const u16* W = (z == 0) ? Wqb : (z == 1) ? Wkb : Wvb;
  const int m0 = blockIdx.x << 7, n0 = blockIdx.y << 7;
  f32x4 acc[4][4] = {};
  gemm_core(xb, W, m0, n0, lsA, lsB, acc);

  const int l  = threadIdx.x & 63;
  const int wr = (threadIdx.x >> 7) & 1, wc = (threadIdx.x >> 6) & 1;
  const int rb = m0 + (wr << 6) + ((l >> 4) << 2);
  const int cb = n0 + (wc << 6) + (l & 15);

  if (z < 2){
    // Q gets the folded softmax scale (base-2 domain); K unscaled
    const float sc = (z == 0) ? QSCALE : 1.0f;
    u16* C = (z == 0) ? Qo : Ko;
    #pragma unroll
    for (int m16 = 0; m16 < 4; ++m16)
      #pragma unroll
      for (int n16 = 0; n16 < 4; ++n16)
        #pragma unroll
        for (int r = 0; r < 4; ++r)
          C[(size_t)(rb + (m16 << 4) + r) * ND + cb + (n16 << 4)] = f2bf(acc[m16][n16][r] * sc);
  } else {
    #pragma unroll
    for (int m16 = 0; m16 < 4; ++m16){
      int srow = rb + (m16 << 4);
      int bi = srow >> 11, s = srow & 2047;
      #pragma unroll
      for (int n16 = 0; n16 < 4; ++n16){
        int col = cb + (n16 << 4);
        u16x4 pk = { f2bf(acc[m16][n16][0]), f2bf(acc[m16][n16][1]),
                     f2bf(acc[m16][n16][2]), f2bf(acc[m16][n16][3]) };
        *(u16x4*)&Vt[((size_t)(bi * 16 + (col >> 6)) * 64 + (col & 63)) * 2048 + s] = pk;
      }
    }
  }
}

// ---------------- output projection: grid (32, 8) ----------------
__global__ __launch_bounds__(256) void gemm_out(
    const u16* __restrict__ ctxb, const u16* __restrict__ Wob,
    const float* __restrict__ bo, float* __restrict__ out)
{
  __shared__ u16 lsA[128*64];
  __shared__ u16 lsB[128*64];
  const int m0 = blockIdx.x << 7, n0 = blockIdx.y << 7;
  f32x4 acc[4][4] = {};
  gemm_core(ctxb, Wob, m0, n0, lsA, lsB, acc);

  const int l  = threadIdx.x & 63;
  const int wr = (threadIdx.x >> 7) & 1, wc = (threadIdx.x >> 6) & 1;
  const int rb = m0 + (wr << 6) + ((l >> 4) << 2);
  const int cb = n0 + (wc << 6) + (l & 15);
  #pragma unroll
  for (int m16 = 0; m16 < 4; ++m16)
    #pragma unroll
    for (int n16 = 0; n16 < 4; ++n16)
      #pragma unroll
      for (int r = 0; r < 4; ++r){
        int col = cb + (n16 << 4);
        out[(size_t)(rb + (m16 << 4) + r) * ND + col] = acc[m16][n16][r] + bo[col];
      }
}

// ---------------- causal flash attention ----------------
// grid 1024 (1D). Block -> (bh, supertile) via XCD-aware map: xcd = bid&7 so all
// 32 supertiles of a (b,h) run on ONE XCD (K/V 512KB stays L2-resident). Longest
// supertiles dispatched first (short tail). 4 waves, wave w owns 16 q-rows.
// K/V 64x64 tiles double-buffered in swizzled LDS via global_load_lds.
// Softmax in base-2 domain (scale pre-folded into Q), diagonal iteration peeled,
// defer-max (THR=8) skips O/l rescale on most iterations, P goes through LDS as
// f32 and is packed to bf16 with v_cvt_pk_bf16_f32 after the transpose read.
__device__ __forceinline__ void stage_tile(const u16* src, int srcStride, u16* lds, int tid){
  const int rl = tid >> 3;
  const int ch = tid & 7;
  const int cs = ch ^ (rl & 7);
  gload_lds16(&src[(size_t)rl * srcStride + cs * 8],        &lds[rl * 64 + ch * 8]);
  gload_lds16(&src[(size_t)(rl + 32) * srcStride + cs * 8], &lds[(rl + 32) * 64 + ch * 8]);
}

template<bool DIAG>
__device__ __forceinline__ void attn_step(
    const u16* lsKcur, const u16* lsVcur, float (*Pfw)[68],
    short8 qf0, short8 qf1,
    float (&m_r)[4], float (&l_r)[4], f32x4 (&acc_o)[4],
    int lr, int lg, int lkB, int qloc)
{
  const char* Kc = (const char*)lsKcur;
  const char* Vc = (const char*)lsVcur;

  short8 kf[4][2], vf[4][2];
  #pragma unroll
  for (int n16 = 0; n16 < 4; ++n16){
    int r  = (n16 << 4) + lr;
    int rx = (r & 7) << 4;
    kf[n16][0] = *(const short8*)(Kc + r * 128 + (lkB ^ rx));
    kf[n16][1] = *(const short8*)(Kc + r * 128 + ((64 + lkB) ^ rx));
    vf[n16][0] = *(const short8*)(Vc + r * 128 + (lkB ^ rx));
    vf[n16][1] = *(const short8*)(Vc + r * 128 + ((64 + lkB) ^ rx));
  }

  // S = Q K^T (already base-2 scores: Q pre-scaled by 1/32*log2e)
  f32x4 s[4];
  #pragma unroll
  for (int n16 = 0; n16 < 4; ++n16){
    f32x4 z = {};
    z = __builtin_amdgcn_mfma_f32_16x16x32_bf16(qf0, kf[n16][0], z, 0, 0, 0);
    z = __builtin_amdgcn_mfma_f32_16x16x32_bf16(qf1, kf[n16][1], z, 0, 0, 0);
    s[n16] = z;
  }
  if (DIAG){
    #pragma unroll
    for (int n16 = 0; n16 < 4; ++n16)
      #pragma unroll
      for (int r = 0; r < 4; ++r)
        if (n16 * 16 + lr > qloc + lg * 4 + r) s[n16][r] = -3e38f;
  }

  // row max (16-lane DPP reduce)
  float pm[4];
  #pragma unroll
  for (int r = 0; r < 4; ++r)
    pm[r] = row16_max(fmaxf(fmaxf(s[0][r], s[1][r]), fmaxf(s[2][r], s[3][r])));

  // defer-max: rescale only when the max grew by more than 8 (P stays <= 2^8)
  bool need = (pm[0] > m_r[0] + 8.f) | (pm[1] > m_r[1] + 8.f) |
              (pm[2] > m_r[2] + 8.f) | (pm[3] > m_r[3] + 8.f);
  if (__any(need)){
    #pragma unroll
    for (int r = 0; r < 4; ++r){
      float mn = fmaxf(m_r[r], pm[r]);
      float e  = EXP2(m_r[r] - mn);
      m_r[r] = mn;
      l_r[r] *= e;
      #pragma unroll
      for (int n16 = 0; n16 < 4; ++n16)
        acc_o[n16][r] *= e;
    }
  }

  // P = exp2(S - m)
  #pragma unroll
  for (int n16 = 0; n16 < 4; ++n16)
    #pragma unroll
    for (int r = 0; r < 4; ++r)
      s[n16][r] = EXP2(s[n16][r] - m_r[r]);
  #pragma unroll
  for (int r = 0; r < 4; ++r)
    l_r[r] += row16_sum((s[0][r] + s[1][r]) + (s[2][r] + s[3][r]));

  // P transpose through wave-private LDS (f32), pack to bf16 after read
  #pragma unroll
  for (int n16 = 0; n16 < 4; ++n16)
    #pragma unroll
    for (int r = 0; r < 4; ++r)
      Pfw[lg * 4 + r][n16 * 16 + lr] = s[n16][r];
  asm volatile("s_waitcnt lgkmcnt(0)" ::: "memory");
  __builtin_amdgcn_sched_barrier(0);
  f32x4 pA = *(const f32x4*)&Pfw[lr][lg * 8];
  f32x4 pB = *(const f32x4*)&Pfw[lr][lg * 8 + 4];
  f32x4 pC = *(const f32x4*)&Pfw[lr][32 + lg * 8];
  f32x4 pD = *(const f32x4*)&Pfw[lr][32 + lg * 8 + 4];
  short8 pa0 = pack8(pA, pB);
  short8 pa1 = pack8(pC, pD);

  // O += P V
  #pragma unroll
  for (int n16 = 0; n16 < 4; ++n16){
    acc_o[n16] = __builtin_amdgcn_mfma_f32_16x16x32_bf16(pa0, vf[n16][0], acc_o[n16], 0, 0, 0);
    acc_o[n16] = __builtin_amdgcn_mfma_f32_16x16x32_bf16(pa1, vf[n16][1], acc_o[n16], 0, 0, 0);
  }
}

__global__ __launch_bounds__(256) void attn_kernel(
    const u16* __restrict__ Q, const u16* __restrict__ K,
    const u16* __restrict__ Vt, u16* __restrict__ ctx)
{
  __shared__ __align__(16) u16 lsK[2][64*64];
  __shared__ __align__(16) u16 lsV[2][64*64];
  __shared__ __align__(16) float Pf[4][16][68];

  const int bid = blockIdx.x;
  const int xcd = bid & 7;
  const int j   = bid >> 3;           // 0..127
  const int bh  = xcd + 8 * (j >> 5); // all 32 supertiles of a bh on one XCD
  const int st  = 31 - (j & 31);      // longest-first within each XCD stream
  const int b = bh >> 4, h = bh & 15;
  const int tid = threadIdx.x;
  const int l = tid & 63, w = tid >> 6;
  const int lr = l & 15, lg = l >> 4;
  const int lkB = lg << 4;
  const int qloc = w << 4;

  const u16* Kb0 = &K[(size_t)(b * NS) * ND + h * 64];
  const u16* Vb0 = &Vt[(size_t)bh * 64 * NS];

  const u16* Qrow = &Q[(size_t)(b * NS + st * 64 + qloc + lr) * ND + h * 64];
  short8 qf0 = *(const short8*)&Qrow[lg * 8];
  short8 qf1 = *(const short8*)&Qrow[32 + lg * 8];

  float m_r[4], l_r[4];
  f32x4 acc_o[4] = {};
  #pragma unroll
  for (int r = 0; r < 4; ++r){ m_r[r] = -3e38f; l_r[r] = 0.f; }

  int cur = 0;
  stage_tile(Kb0, ND, &lsK[0][0], tid);
  stage_tile(Vb0, NS, &lsV[0][0], tid);
  __syncthreads();

  #pragma unroll 1
  for (int t = 0; t < st; ++t){
    stage_tile(&Kb0[(size_t)(t + 1) * 64 * ND], ND, &lsK[cur ^ 1][0], tid);
    stage_tile(&Vb0[(t + 1) * 64],              NS, &lsV[cur ^ 1][0], tid);
    attn_step<false>(&lsK[cur][0], &lsV[cur][0], Pf[w], qf0, qf1,
                     m_r, l_r, acc_o, lr, lg, lkB, qloc);
    __syncthreads();
    cur ^= 1;
  }
  // diagonal tile (mask applied here only)
  attn_step<true>(&lsK[cur][0], &lsV[cur][0], Pf[w], qf0, qf1,
                  m_r, l_r, acc_o, lr, lg, lkB, qloc);

  #pragma unroll
  for (int r = 0; r < 4; ++r){
    float inv = RCP(l_r[r]);
    int qg = st * 64 + qloc + lg * 4 + r;
    #pragma unroll
    for (int n16 = 0; n16 < 4; ++n16)
      ctx[(size_t)(b * NS + qg) * ND + h * 64 + n16 * 16 + lr] = f2bf(acc_o[n16][r] * inv);
  }
}

extern "C" void kernel_launch(void* const* d_in, const int* in_sizes, int n_in,
                              void* d_out, int out_size, void* d_ws, size_t ws_size,
                              hipStream_t stream)
{
  const float* x  = (const float*)d_in[0];
  const float* Wq = (const float*)d_in[1];
  const float* Wk = (const float*)d_in[2];
  const float* Wv = (const float*)d_in[3];
  const float* Wo = (const float*)d_in[4];
  const float* bo = (const float*)d_in[5];
  float* out = (float*)d_out;
  char* ws = (char*)d_ws;

  u16* xb  = (u16*)(ws);
  u16* Wqb = (u16*)(ws + (8u  << 20));
  u16* Wkb = (u16*)(ws + (10u << 20));
  u16* Wvb = (u16*)(ws + (12u << 20));
  u16* Wob = (u16*)(ws + (14u << 20));
  u16* Qb  = (u16*)(ws + (16u << 20));
  u16* Kb  = (u16*)(ws + (24u << 20));
  u16* Vtb = (u16*)(ws + (32u << 20));
  u16* Cb  = (u16*)(ws + (40u << 20));

  cvt_kernel<<<4096, 256, 0, stream>>>(x, xb, NM * ND);
  cvt4_kernel<<<dim3(1024, 4), 256, 0, stream>>>(Wq, Wk, Wv, Wo, Wqb, Wkb, Wvb, Wob);

  gemm_qkv<<<dim3(32, 8, 3), 256, 0, stream>>>(xb, Wqb, Wkb, Wvb, Qb, Kb, Vtb);
  attn_kernel<<<1024, 256, 0, stream>>>(Qb, Kb, Vtb, Cb);
  gemm_out<<<dim3(32, 8), 256, 0, stream>>>(Cb, Wob, bo, out);
}

// Round 6
// 136.487 us; speedup vs baseline: 2.9984x; 1.0290x over previous
//
#include <hip/hip_runtime.h>
#include <hip/hip_bf16.h>
#include <stdint.h>

typedef unsigned short u16;
typedef __attribute__((ext_vector_type(8))) short short8;
typedef __attribute__((ext_vector_type(4))) float f32x4;
typedef __attribute__((ext_vector_type(16))) float f32x16;
typedef __attribute__((ext_vector_type(4))) u16 u16x4;

#define NB 2
#define NS 2048
#define ND 1024
#define NH 16
#define NM 4096   // NB*NS

// 1/sqrt(1024) * log2(e): folded into Q so QK^T scores are base-2 scores
#define QSCALE 0.045084220f

#if __has_builtin(__builtin_amdgcn_exp2f)
#define EXP2(x) __builtin_amdgcn_exp2f(x)
#else
#define EXP2(x) exp2f(x)
#endif
#if __has_builtin(__builtin_amdgcn_rcpf)
#define RCP(x) __builtin_amdgcn_rcpf(x)
#else
#define RCP(x) (1.0f / (x))
#endif

// RNE f32 -> bf16
__device__ __forceinline__ u16 f2bf(float f){
  union { float f; unsigned u; } v; v.f = f;
  unsigned r = v.u + 0x7fff + ((v.u >> 16) & 1);
  return (u16)(r >> 16);
}

// packed f32 pair -> 2x bf16 in one u32 (hardware RNE); lo -> bits[15:0]
__device__ __forceinline__ unsigned cvtpk(float lo, float hi){
  unsigned r;
  asm("v_cvt_pk_bf16_f32 %0, %1, %2" : "=v"(r) : "v"(lo), "v"(hi));
  return r;
}

// v_permlane32_swap_b32: e<lanes32-63> <-> o<lanes0-31>.
// After: e = (hi?partner_o:own_e), o = (hi?own_o:partner_e) per lane.
__device__ __forceinline__ void pl32swap(unsigned &e, unsigned &o){
  asm("v_permlane32_swap_b32 %0, %1" : "+v"(e), "+v"(o));
}

__device__ __forceinline__ void gload_lds16(const u16* g, u16* l){
  __builtin_amdgcn_global_load_lds(
      (const __attribute__((address_space(1))) unsigned int*)g,
      (__attribute__((address_space(3))) unsigned int*)l, 16, 0, 0);
}

__device__ __forceinline__ f32x16 mfma32(short8 a, short8 b, f32x16 c){
  return __builtin_amdgcn_mfma_f32_32x32x16_bf16(a, b, c, 0, 0, 0);
}

// ---------------- f32 -> bf16 convert ----------------
__global__ void cvt_kernel(const float* __restrict__ src, u16* __restrict__ dst, int n){
  int i = (blockIdx.x * blockDim.x + threadIdx.x) * 4;
  if (i < n){
    float4 v = *(const float4*)(src + i);
    u16x4 o = { f2bf(v.x), f2bf(v.y), f2bf(v.z), f2bf(v.w) };
    *(u16x4*)(dst + i) = o;
  }
}

__global__ void cvt4_kernel(const float* __restrict__ a, const float* __restrict__ b,
                            const float* __restrict__ c, const float* __restrict__ d,
                            u16* __restrict__ oa, u16* __restrict__ ob,
                            u16* __restrict__ oc, u16* __restrict__ od){
  const float* s; u16* o;
  switch (blockIdx.y){
    case 0: s = a; o = oa; break;
    case 1: s = b; o = ob; break;
    case 2: s = c; o = oc; break;
    default: s = d; o = od; break;
  }
  int i = (blockIdx.x * blockDim.x + threadIdx.x) * 4;
  float4 v = *(const float4*)(s + i);
  u16x4 pk = { f2bf(v.x), f2bf(v.y), f2bf(v.z), f2bf(v.w) };
  *(u16x4*)(o + i) = pk;
}

// ---------------- NT GEMM core ----------------
__device__ __forceinline__ void gemm_core(
    const u16* __restrict__ A, const u16* __restrict__ W,
    int m0, int n0, u16* lsA, u16* lsB, f32x4 acc[4][4])
{
  const int tid = threadIdx.x;
  const int l   = tid & 63;
  const int wr  = (tid >> 7) & 1;
  const int wc  = (tid >> 6) & 1;
  const int lr  = l & 15;
  const int lkb = (l >> 4) << 4;
  const int sr  = tid >> 3;
  const int scb = (tid & 7) << 4;

  for (int kt = 0; kt < 16; ++kt){
    const int k0 = kt << 6;
    #pragma unroll
    for (int i = 0; i < 4; ++i){
      int r   = (i << 5) + sr;
      int cbs = scb ^ ((r & 7) << 4);
      gload_lds16(&A[(size_t)(m0 + r) * ND + k0 + (cbs >> 1)], &lsA[r * 64 + (scb >> 1)]);
      gload_lds16(&W[(size_t)(n0 + r) * ND + k0 + (cbs >> 1)], &lsB[r * 64 + (scb >> 1)]);
    }
    __syncthreads();

    short8 af[4][2], bf[4][2];
    #pragma unroll
    for (int m16 = 0; m16 < 4; ++m16){
      int r  = (wr << 6) + (m16 << 4) + lr;
      int rx = (r & 7) << 4;
      #pragma unroll
      for (int ks = 0; ks < 2; ++ks){
        int off = r * 128 + (((ks << 6) + lkb) ^ rx);
        af[m16][ks] = *(const short8*)((const char*)lsA + off);
      }
    }
    #pragma unroll
    for (int n16 = 0; n16 < 4; ++n16){
      int r  = (wc << 6) + (n16 << 4) + lr;
      int rx = (r & 7) << 4;
      #pragma unroll
      for (int ks = 0; ks < 2; ++ks){
        int off = r * 128 + (((ks << 6) + lkb) ^ rx);
        bf[n16][ks] = *(const short8*)((const char*)lsB + off);
      }
    }
    #pragma unroll
    for (int m16 = 0; m16 < 4; ++m16)
      #pragma unroll
      for (int n16 = 0; n16 < 4; ++n16){
        acc[m16][n16] = __builtin_amdgcn_mfma_f32_16x16x32_bf16(af[m16][0], bf[n16][0], acc[m16][n16], 0, 0, 0);
        acc[m16][n16] = __builtin_amdgcn_mfma_f32_16x16x32_bf16(af[m16][1], bf[n16][1], acc[m16][n16], 0, 0, 0);
      }
    __syncthreads();
  }
}

// ---------------- fused QKV projection: grid (32, 8, 3) ----------------
__global__ __launch_bounds__(256) void gemm_qkv(
    const u16* __restrict__ xb,
    const u16* __restrict__ Wqb, const u16* __restrict__ Wkb, const u16* __restrict__ Wvb,
    u16* __restrict__ Qo, u16* __restrict__ Ko, u16* __restrict__ Vt)
{
  __shared__ u16 lsA[128*64];
  __shared__ u16 lsB[128*64];
  const int z = blockIdx.z;
  const u16* W = (z == 0) ? Wqb : (z == 1) ? Wkb : Wvb;
  const int m0 = blockIdx.x << 7, n0 = blockIdx.y << 7;
  f32x4 acc[4][4] = {};
  gemm_core(xb, W, m0, n0, lsA, lsB, acc);

  const int l  = threadIdx.x & 63;
  const int wr = (threadIdx.x >> 7) & 1, wc = (threadIdx.x >> 6) & 1;
  const int rb = m0 + (wr << 6) + ((l >> 4) << 2);
  const int cb = n0 + (wc << 6) + (l & 15);

  if (z < 2){
    // Q gets the folded softmax scale (base-2 domain); K unscaled
    const float sc = (z == 0) ? QSCALE : 1.0f;
    u16* C = (z == 0) ? Qo : Ko;
    #pragma unroll
    for (int m16 = 0; m16 < 4; ++m16)
      #pragma unroll
      for (int n16 = 0; n16 < 4; ++n16)
        #pragma unroll
        for (int r = 0; r < 4; ++r)
          C[(size_t)(rb + (m16 << 4) + r) * ND + cb + (n16 << 4)] = f2bf(acc[m16][n16][r] * sc);
  } else {
    #pragma unroll
    for (int m16 = 0; m16 < 4; ++m16){
      int srow = rb + (m16 << 4);
      int bi = srow >> 11, s = srow & 2047;
      #pragma unroll
      for (int n16 = 0; n16 < 4; ++n16){
        int col = cb + (n16 << 4);
        u16x4 pk = { f2bf(acc[m16][n16][0]), f2bf(acc[m16][n16][1]),
                     f2bf(acc[m16][n16][2]), f2bf(acc[m16][n16][3]) };
        *(u16x4*)&Vt[((size_t)(bi * 16 + (col >> 6)) * 64 + (col & 63)) * 2048 + s] = pk;
      }
    }
  }
}

// ---------------- output projection: grid (32, 8) ----------------
__global__ __launch_bounds__(256) void gemm_out(
    const u16* __restrict__ ctxb, const u16* __restrict__ Wob,
    const float* __restrict__ bo, float* __restrict__ out)
{
  __shared__ u16 lsA[128*64];
  __shared__ u16 lsB[128*64];
  const int m0 = blockIdx.x << 7, n0 = blockIdx.y << 7;
  f32x4 acc[4][4] = {};
  gemm_core(ctxb, Wob, m0, n0, lsA, lsB, acc);

  const int l  = threadIdx.x & 63;
  const int wr = (threadIdx.x >> 7) & 1, wc = (threadIdx.x >> 6) & 1;
  const int rb = m0 + (wr << 6) + ((l >> 4) << 2);
  const int cb = n0 + (wc << 6) + (l & 15);
  #pragma unroll
  for (int m16 = 0; m16 < 4; ++m16)
    #pragma unroll
    for (int n16 = 0; n16 < 4; ++n16)
      #pragma unroll
      for (int r = 0; r < 4; ++r){
        int col = cb + (n16 << 4);
        out[(size_t)(rb + (m16 << 4) + r) * ND + col] = acc[m16][n16][r] + bo[col];
      }
}

// ---------------- causal flash attention: swapped-QK^T 32x32 form ----------------
// grid 512. bid&7 = XCD; 4 (b,h) streams per XCD (K/V L2-resident); 16 blocks per
// bh = 128-q-row supertiles, longest-first. 4 waves x 32 q-rows. Per kv-iter the
// block stages 64x64 K and Vt tiles (double-buffered, XOR-swizzled, global_load_lds).
// S^T = K*Q^T via mfma_32x32x16 => lane owns full P-row for q=lane&31 (plus the
// partner lane across the hi split): softmax is in-register trees + 1 shfl_xor(32);
// P repacked to PV A-fragments with v_cvt_pk_bf16_f32 + v_permlane32_swap_b32.
// O accumulates via mfma(A=P, B=Vt-frag). No P LDS round trip, scalar m/l state.
__device__ __forceinline__ void stage_tile(const u16* src, int srcStride, u16* lds, int tid){
  const int rl = tid >> 3;
  const int ch = tid & 7;
  const int cs = ch ^ (rl & 7);
  gload_lds16(&src[(size_t)rl * srcStride + cs * 8],        &lds[rl * 64 + ch * 8]);
  gload_lds16(&src[(size_t)(rl + 32) * srcStride + cs * 8], &lds[(rl + 32) * 64 + ch * 8]);
}

__global__ __launch_bounds__(256) void attn_kernel(
    const u16* __restrict__ Q, const u16* __restrict__ K,
    const u16* __restrict__ Vt, u16* __restrict__ ctx)
{
  __shared__ __align__(16) u16 lsK[2][64*64];
  __shared__ __align__(16) u16 lsV[2][64*64];

  const int bid = blockIdx.x;
  const int xcd = bid & 7;
  const int j   = bid >> 3;            // 0..63
  const int bh  = xcd + 8 * (j >> 4);  // 4 bh per XCD
  const int st  = 15 - (j & 15);       // longest-first
  const int b = bh >> 4, h = bh & 15;
  const int tid = threadIdx.x;
  const int l = tid & 63, w = tid >> 6;
  const int q5 = l & 31, hi = l >> 5;
  const int qb   = st * 128 + w * 32;  // wave q base
  const int qgl  = qb + q5;            // lane's q row
  const int qmax = qb + 31;
  const int tb   = 2 * st + 1;         // last kv tile

  const u16* Kb0 = &K[(size_t)(b * NS) * ND + h * 64];
  const u16* Vb0 = &Vt[(size_t)bh * 64 * NS];

  // Q fragments (B-operand): lane holds Q[qgl][16ks+8hi+(0..7)]
  short8 qf[4];
  {
    const u16* Qrow = &Q[(size_t)(b * NS + qgl) * ND + h * 64 + hi * 8];
    #pragma unroll
    for (int ks = 0; ks < 4; ++ks)
      qf[ks] = *(const short8*)&Qrow[ks * 16];
  }

  float m_r = -3e38f, l_r = 0.f;
  f32x16 accA = {}, accB = {};

  int cur = 0;
  stage_tile(Kb0, ND, &lsK[0][0], tid);
  stage_tile(Vb0, NS, &lsV[0][0], tid);
  __syncthreads();

  #pragma unroll 1
  for (int t = 0; t <= tb; ++t){
    if (t < tb){
      stage_tile(&Kb0[(size_t)(t + 1) * 64 * ND], ND, &lsK[cur ^ 1][0], tid);
      stage_tile(&Vb0[(t + 1) * 64],              NS, &lsV[cur ^ 1][0], tid);
    }
    if (t * 64 <= qmax){   // wave-uniform: skip fully-masked tiles
      const char* Kc = (const char*)&lsK[cur][0];
      const char* Vc = (const char*)&lsV[cur][0];
      const int swz = q5 & 7;

      // ---- S^T = K * Q^T (2 kv half-tiles x 4 hd-steps) ----
      f32x16 s0 = {}, s1 = {};
      #pragma unroll
      for (int ks = 0; ks < 4; ++ks){
        int c0 = ((2 * ks + hi) ^ swz) << 4;
        short8 k0 = *(const short8*)(Kc + q5 * 128 + c0);
        short8 k1 = *(const short8*)(Kc + (q5 + 32) * 128 + c0);
        s0 = mfma32(k0, qf[ks], s0);
        s1 = mfma32(k1, qf[ks], s1);
      }

      // causal mask (only on tiles crossing this wave's diagonal)
      if (t * 64 + 63 > qb){
        #pragma unroll
        for (int r = 0; r < 16; ++r){
          int kl = t * 64 + (r & 3) + 8 * (r >> 2) + 4 * hi;
          if (kl > qgl)      s0[r] = -3e38f;
          if (kl + 32 > qgl) s1[r] = -3e38f;
        }
      }

      // ---- row max: in-lane tree + hi-swap ----
      float mx[16];
      #pragma unroll
      for (int r = 0; r < 16; ++r) mx[r] = fmaxf(s0[r], s1[r]);
      #pragma unroll
      for (int stp = 8; stp > 0; stp >>= 1)
        #pragma unroll
        for (int r = 0; r < stp; ++r) mx[r] = fmaxf(mx[r], mx[r + stp]);
      float pm = fmaxf(mx[0], __shfl_xor(mx[0], 32));

      // defer-max (THR=8): rescale only when max grew enough to matter
      if (__any(pm > m_r + 8.f)){
        float mn = fmaxf(m_r, pm);
        float e  = EXP2(m_r - mn);
        m_r = mn; l_r *= e;
        #pragma unroll
        for (int r = 0; r < 16; ++r){ accA[r] *= e; accB[r] *= e; }
      }

      // ---- P = exp2(S - m); row sum ----
      #pragma unroll
      for (int r = 0; r < 16; ++r){
        s0[r] = EXP2(s0[r] - m_r);
        s1[r] = EXP2(s1[r] - m_r);
      }
      float sm[16];
      #pragma unroll
      for (int r = 0; r < 16; ++r) sm[r] = s0[r] + s1[r];
      #pragma unroll
      for (int stp = 8; stp > 0; stp >>= 1)
        #pragma unroll
        for (int r = 0; r < stp; ++r) sm[r] += sm[r + stp];
      l_r += sm[0] + __shfl_xor(sm[0], 32);

      // ---- pack P -> bf16 words; permlane32_swap assembles A-fragments ----
      // pw[m][g][i]: k = 32m + 8g + 4hi + (2i..2i+1) for q=lane&31
      unsigned pw[2][4][2];
      #pragma unroll
      for (int g = 0; g < 4; ++g){
        pw[0][g][0] = cvtpk(s0[4*g],     s0[4*g + 1]);
        pw[0][g][1] = cvtpk(s0[4*g + 2], s0[4*g + 3]);
        pw[1][g][0] = cvtpk(s1[4*g],     s1[4*g + 1]);
        pw[1][g][1] = cvtpk(s1[4*g + 2], s1[4*g + 3]);
      }
      #pragma unroll
      for (int m = 0; m < 2; ++m)
        #pragma unroll
        for (int kp = 0; kp < 2; ++kp)
          #pragma unroll
          for (int i = 0; i < 2; ++i)
            pl32swap(pw[m][2*kp][i], pw[m][2*kp + 1][i]);
      // now frag(ks): [pw[m][2kp][0], pw[m][2kp][1], pw[m][2kp+1][0], pw[m][2kp+1][1]]
      // holds P[q][16ks+8hi+(0..7)] with m=ks>>1, kp=ks&1.

      // ---- O += P * V (B from pre-transposed Vt tile: contiguous 16B reads) ----
      #pragma unroll
      for (int ks = 0; ks < 4; ++ks){
        const int m = ks >> 1, kp = ks & 1;
        union { unsigned u[4]; short8 s8; } pa;
        pa.u[0] = pw[m][2*kp][0];
        pa.u[1] = pw[m][2*kp][1];
        pa.u[2] = pw[m][2*kp + 1][0];
        pa.u[3] = pw[m][2*kp + 1][1];
        int c0 = ((2 * ks + hi) ^ swz) << 4;
        short8 v0 = *(const short8*)(Vc + q5 * 128 + c0);
        short8 v1 = *(const short8*)(Vc + (q5 + 32) * 128 + c0);
        accA = mfma32(pa.s8, v0, accA);
        accB = mfma32(pa.s8, v1, accB);
      }
    }
    __syncthreads();
    cur ^= 1;
  }

  // ---- epilogue: redistribute 1/l to register q-rows, store ----
  float inv = RCP(l_r);
  #pragma unroll
  for (int r = 0; r < 16; ++r){
    int qrow = (r & 3) + 8 * (r >> 2) + 4 * hi;
    float iv = __shfl(inv, (l & 32) | qrow, 64);
    u16* crow = &ctx[(size_t)(b * NS + qb + qrow) * ND + h * 64 + q5];
    crow[0]  = f2bf(accA[r] * iv);
    crow[32] = f2bf(accB[r] * iv);
  }
}

extern "C" void kernel_launch(void* const* d_in, const int* in_sizes, int n_in,
                              void* d_out, int out_size, void* d_ws, size_t ws_size,
                              hipStream_t stream)
{
  const float* x  = (const float*)d_in[0];
  const float* Wq = (const float*)d_in[1];
  const float* Wk = (const float*)d_in[2];
  const float* Wv = (const float*)d_in[3];
  const float* Wo = (const float*)d_in[4];
  const float* bo = (const float*)d_in[5];
  float* out = (float*)d_out;
  char* ws = (char*)d_ws;

  u16* xb  = (u16*)(ws);
  u16* Wqb = (u16*)(ws + (8u  << 20));
  u16* Wkb = (u16*)(ws + (10u << 20));
  u16* Wvb = (u16*)(ws + (12u << 20));
  u16* Wob = (u16*)(ws + (14u << 20));
  u16* Qb  = (u16*)(ws + (16u << 20));
  u16* Kb  = (u16*)(ws + (24u << 20));
  u16* Vtb = (u16*)(ws + (32u << 20));
  u16* Cb  = (u16*)(ws + (40u << 20));

  cvt_kernel<<<4096, 256, 0, stream>>>(x, xb, NM * ND);
  cvt4_kernel<<<dim3(1024, 4), 256, 0, stream>>>(Wq, Wk, Wv, Wo, Wqb, Wkb, Wvb, Wob);

  gemm_qkv<<<dim3(32, 8, 3), 256, 0, stream>>>(xb, Wqb, Wkb, Wvb, Qb, Kb, Vtb);
  attn_kernel<<<512, 256, 0, stream>>>(Qb, Kb, Vtb, Cb);
  gemm_out<<<dim3(32, 8), 256, 0, stream>>>(Cb, Wob, bo, out);
}

// Round 7
// 133.753 us; speedup vs baseline: 3.0597x; 1.0204x over previous
//
#include <hip/hip_runtime.h>
#include <hip/hip_bf16.h>
#include <stdint.h>

typedef unsigned short u16;
typedef __attribute__((ext_vector_type(8))) short short8;
typedef __attribute__((ext_vector_type(4))) float f32x4;
typedef __attribute__((ext_vector_type(16))) float f32x16;
typedef __attribute__((ext_vector_type(4))) u16 u16x4;

#define NB 2
#define NS 2048
#define ND 1024
#define NH 16
#define NM 4096   // NB*NS

// 1/sqrt(1024) * log2(e): folded into Q so QK^T scores are base-2 scores
#define QSCALE 0.045084220f

// single-instruction exp2 (transcendental); avoid exp2f libcall
#if __has_builtin(__builtin_amdgcn_exp2f)
#define EXP2(x) __builtin_amdgcn_exp2f(x)
#else
__device__ __forceinline__ float __exp2_asm(float x){
  float r;
  asm("v_exp_f32 %0, %1" : "=v"(r) : "v"(x));
  return r;
}
#define EXP2(x) __exp2_asm(x)
#endif
#if __has_builtin(__builtin_amdgcn_rcpf)
#define RCP(x) __builtin_amdgcn_rcpf(x)
#else
#define RCP(x) (1.0f / (x))
#endif

// RNE f32 -> bf16
__device__ __forceinline__ u16 f2bf(float f){
  union { float f; unsigned u; } v; v.f = f;
  unsigned r = v.u + 0x7fff + ((v.u >> 16) & 1);
  return (u16)(r >> 16);
}

// packed f32 pair -> 2x bf16 in one u32 (hardware RNE); lo -> bits[15:0]
__device__ __forceinline__ unsigned cvtpk(float lo, float hi){
  unsigned r;
  asm("v_cvt_pk_bf16_f32 %0, %1, %2" : "=v"(r) : "v"(lo), "v"(hi));
  return r;
}

// v_permlane32_swap_b32: swap lane halves between the two operands
__device__ __forceinline__ void pl32swap(unsigned &e, unsigned &o){
  asm("v_permlane32_swap_b32 %0, %1" : "+v"(e), "+v"(o));
}

__device__ __forceinline__ void gload_lds16(const u16* g, u16* l){
  __builtin_amdgcn_global_load_lds(
      (const __attribute__((address_space(1))) unsigned int*)g,
      (__attribute__((address_space(3))) unsigned int*)l, 16, 0, 0);
}

__device__ __forceinline__ f32x16 mfma32(short8 a, short8 b, f32x16 c){
  return __builtin_amdgcn_mfma_f32_32x32x16_bf16(a, b, c, 0, 0, 0);
}

// ---------------- f32 -> bf16 convert ----------------
__global__ void cvt_kernel(const float* __restrict__ src, u16* __restrict__ dst, int n){
  int i = (blockIdx.x * blockDim.x + threadIdx.x) * 4;
  if (i < n){
    float4 v = *(const float4*)(src + i);
    u16x4 o = { f2bf(v.x), f2bf(v.y), f2bf(v.z), f2bf(v.w) };
    *(u16x4*)(dst + i) = o;
  }
}

__global__ void cvt4_kernel(const float* __restrict__ a, const float* __restrict__ b,
                            const float* __restrict__ c, const float* __restrict__ d,
                            u16* __restrict__ oa, u16* __restrict__ ob,
                            u16* __restrict__ oc, u16* __restrict__ od){
  const float* s; u16* o;
  switch (blockIdx.y){
    case 0: s = a; o = oa; break;
    case 1: s = b; o = ob; break;
    case 2: s = c; o = oc; break;
    default: s = d; o = od; break;
  }
  int i = (blockIdx.x * blockDim.x + threadIdx.x) * 4;
  float4 v = *(const float4*)(s + i);
  u16x4 pk = { f2bf(v.x), f2bf(v.y), f2bf(v.z), f2bf(v.w) };
  *(u16x4*)(o + i) = pk;
}

// ---------------- NT GEMM core ----------------
__device__ __forceinline__ void gemm_core(
    const u16* __restrict__ A, const u16* __restrict__ W,
    int m0, int n0, u16* lsA, u16* lsB, f32x4 acc[4][4])
{
  const int tid = threadIdx.x;
  const int l   = tid & 63;
  const int wr  = (tid >> 7) & 1;
  const int wc  = (tid >> 6) & 1;
  const int lr  = l & 15;
  const int lkb = (l >> 4) << 4;
  const int sr  = tid >> 3;
  const int scb = (tid & 7) << 4;

  for (int kt = 0; kt < 16; ++kt){
    const int k0 = kt << 6;
    #pragma unroll
    for (int i = 0; i < 4; ++i){
      int r   = (i << 5) + sr;
      int cbs = scb ^ ((r & 7) << 4);
      gload_lds16(&A[(size_t)(m0 + r) * ND + k0 + (cbs >> 1)], &lsA[r * 64 + (scb >> 1)]);
      gload_lds16(&W[(size_t)(n0 + r) * ND + k0 + (cbs >> 1)], &lsB[r * 64 + (scb >> 1)]);
    }
    __syncthreads();

    short8 af[4][2], bf[4][2];
    #pragma unroll
    for (int m16 = 0; m16 < 4; ++m16){
      int r  = (wr << 6) + (m16 << 4) + lr;
      int rx = (r & 7) << 4;
      #pragma unroll
      for (int ks = 0; ks < 2; ++ks){
        int off = r * 128 + (((ks << 6) + lkb) ^ rx);
        af[m16][ks] = *(const short8*)((const char*)lsA + off);
      }
    }
    #pragma unroll
    for (int n16 = 0; n16 < 4; ++n16){
      int r  = (wc << 6) + (n16 << 4) + lr;
      int rx = (r & 7) << 4;
      #pragma unroll
      for (int ks = 0; ks < 2; ++ks){
        int off = r * 128 + (((ks << 6) + lkb) ^ rx);
        bf[n16][ks] = *(const short8*)((const char*)lsB + off);
      }
    }
    #pragma unroll
    for (int m16 = 0; m16 < 4; ++m16)
      #pragma unroll
      for (int n16 = 0; n16 < 4; ++n16){
        acc[m16][n16] = __builtin_amdgcn_mfma_f32_16x16x32_bf16(af[m16][0], bf[n16][0], acc[m16][n16], 0, 0, 0);
        acc[m16][n16] = __builtin_amdgcn_mfma_f32_16x16x32_bf16(af[m16][1], bf[n16][1], acc[m16][n16], 0, 0, 0);
      }
    __syncthreads();
  }
}

// ---------------- fused QKV projection: grid (32, 8, 3) ----------------
__global__ __launch_bounds__(256) void gemm_qkv(
    const u16* __restrict__ xb,
    const u16* __restrict__ Wqb, const u16* __restrict__ Wkb, const u16* __restrict__ Wvb,
    u16* __restrict__ Qo, u16* __restrict__ Ko, u16* __restrict__ Vt)
{
  __shared__ u16 lsA[128*64];
  __shared__ u16 lsB[128*64];
  const int z = blockIdx.z;
  const u16* W = (z == 0) ? Wqb : (z == 1) ? Wkb : Wvb;
  const int m0 = blockIdx.x << 7, n0 = blockIdx.y << 7;
  f32x4 acc[4][4] = {};
  gemm_core(xb, W, m0, n0, lsA, lsB, acc);

  const int l  = threadIdx.x & 63;
  const int wr = (threadIdx.x >> 7) & 1, wc = (threadIdx.x >> 6) & 1;
  const int rb = m0 + (wr << 6) + ((l >> 4) << 2);
  const int cb = n0 + (wc << 6) + (l & 15);

  if (z < 2){
    const float sc = (z == 0) ? QSCALE : 1.0f;
    u16* C = (z == 0) ? Qo : Ko;
    #pragma unroll
    for (int m16 = 0; m16 < 4; ++m16)
      #pragma unroll
      for (int n16 = 0; n16 < 4; ++n16)
        #pragma unroll
        for (int r = 0; r < 4; ++r)
          C[(size_t)(rb + (m16 << 4) + r) * ND + cb + (n16 << 4)] = f2bf(acc[m16][n16][r] * sc);
  } else {
    #pragma unroll
    for (int m16 = 0; m16 < 4; ++m16){
      int srow = rb + (m16 << 4);
      int bi = srow >> 11, s = srow & 2047;
      #pragma unroll
      for (int n16 = 0; n16 < 4; ++n16){
        int col = cb + (n16 << 4);
        u16x4 pk = { f2bf(acc[m16][n16][0]), f2bf(acc[m16][n16][1]),
                     f2bf(acc[m16][n16][2]), f2bf(acc[m16][n16][3]) };
        *(u16x4*)&Vt[((size_t)(bi * 16 + (col >> 6)) * 64 + (col & 63)) * 2048 + s] = pk;
      }
    }
  }
}

// ---------------- output projection: grid (32, 8) ----------------
__global__ __launch_bounds__(256) void gemm_out(
    const u16* __restrict__ ctxb, const u16* __restrict__ Wob,
    const float* __restrict__ bo, float* __restrict__ out)
{
  __shared__ u16 lsA[128*64];
  __shared__ u16 lsB[128*64];
  const int m0 = blockIdx.x << 7, n0 = blockIdx.y << 7;
  f32x4 acc[4][4] = {};
  gemm_core(ctxb, Wob, m0, n0, lsA, lsB, acc);

  const int l  = threadIdx.x & 63;
  const int wr = (threadIdx.x >> 7) & 1, wc = (threadIdx.x >> 6) & 1;
  const int rb = m0 + (wr << 6) + ((l >> 4) << 2);
  const int cb = n0 + (wc << 6) + (l & 15);
  #pragma unroll
  for (int m16 = 0; m16 < 4; ++m16)
    #pragma unroll
    for (int n16 = 0; n16 < 4; ++n16)
      #pragma unroll
      for (int r = 0; r < 4; ++r){
        int col = cb + (n16 << 4);
        out[(size_t)(rb + (m16 << 4) + r) * ND + col] = acc[m16][n16][r] + bo[col];
      }
}

// ---------------- causal flash attention: pipelined swapped-QK^T 32x32 ----------------
// grid 512, XCD-pinned streams (K/V L2-resident). 4 waves x 32 q-rows per block.
// 2-tile in-wave software pipeline with a 3-ring LDS buffer, ONE barrier/iter:
//   iter t: stage(t+2) | QK-MFMA(t+1) from ring[(t+1)%3] | softmax(t)+PV(t) from ring[t%3]
// The softmax VALU chain of tile t overlaps the QK MFMA chain of tile t+1.
// Race-freedom: stage(t+2) overwrites ring[(t-1)%3], last read before iter (t-1)'s
// barrier; each wave's waitcnt-before-barrier drains its reads first.
__device__ __forceinline__ void stage_tile(const u16* src, int srcStride, u16* lds, int tid){
  const int rl = tid >> 3;
  const int ch = tid & 7;
  const int cs = ch ^ (rl & 7);
  gload_lds16(&src[(size_t)rl * srcStride + cs * 8],        &lds[rl * 64 + ch * 8]);
  gload_lds16(&src[(size_t)(rl + 32) * srcStride + cs * 8], &lds[(rl + 32) * 64 + ch * 8]);
}

// QK^T MFMA cluster: raw base-2 scores of one 64-kv tile into (s0, s1)
__device__ __forceinline__ void qk_tile(const u16* lsKt, const short8 qf[4],
                                        int q5, int hi, f32x16 &s0, f32x16 &s1){
  const char* Kc = (const char*)lsKt;
  const int swz = q5 & 7;
  f32x16 a = {}, b = {};
  __builtin_amdgcn_s_setprio(1);
  #pragma unroll
  for (int ks = 0; ks < 4; ++ks){
    int c0 = ((2 * ks + hi) ^ swz) << 4;
    short8 k0 = *(const short8*)(Kc + q5 * 128 + c0);
    short8 k1 = *(const short8*)(Kc + (q5 + 32) * 128 + c0);
    a = mfma32(k0, qf[ks], a);
    b = mfma32(k1, qf[ks], b);
  }
  __builtin_amdgcn_s_setprio(0);
  s0 = a; s1 = b;
}

// softmax (online, base-2, defer-max THR=8) + pack + PV MFMA cluster
__device__ __forceinline__ void sm_pv(f32x16 s0, f32x16 s1, const u16* lsVt,
                                      int t, int qb, int qgl, int q5, int hi,
                                      float &m_r, float &l_r, f32x16 &accA, f32x16 &accB){
  // causal mask (only tiles crossing this wave's diagonal)
  if (t * 64 + 63 > qb){
    #pragma unroll
    for (int r = 0; r < 16; ++r){
      int kl = t * 64 + (r & 3) + 8 * (r >> 2) + 4 * hi;
      if (kl > qgl)      s0[r] = -3e38f;
      if (kl + 32 > qgl) s1[r] = -3e38f;
    }
  }
  // row max: in-lane tree + hi-swap
  float mx[16];
  #pragma unroll
  for (int r = 0; r < 16; ++r) mx[r] = fmaxf(s0[r], s1[r]);
  #pragma unroll
  for (int stp = 8; stp > 0; stp >>= 1)
    #pragma unroll
    for (int r = 0; r < stp; ++r) mx[r] = fmaxf(mx[r], mx[r + stp]);
  float pm = fmaxf(mx[0], __shfl_xor(mx[0], 32));

  if (__any(pm > m_r + 8.f)){
    float mn = fmaxf(m_r, pm);
    float e  = EXP2(m_r - mn);
    m_r = mn; l_r *= e;
    #pragma unroll
    for (int r = 0; r < 16; ++r){ accA[r] *= e; accB[r] *= e; }
  }

  #pragma unroll
  for (int r = 0; r < 16; ++r){
    s0[r] = EXP2(s0[r] - m_r);
    s1[r] = EXP2(s1[r] - m_r);
  }
  float sm[16];
  #pragma unroll
  for (int r = 0; r < 16; ++r) sm[r] = s0[r] + s1[r];
  #pragma unroll
  for (int stp = 8; stp > 0; stp >>= 1)
    #pragma unroll
    for (int r = 0; r < stp; ++r) sm[r] += sm[r + stp];
  l_r += sm[0] + __shfl_xor(sm[0], 32);

  // pack P -> bf16; permlane32_swap assembles A-fragments
  unsigned pw[2][4][2];
  #pragma unroll
  for (int g = 0; g < 4; ++g){
    pw[0][g][0] = cvtpk(s0[4*g],     s0[4*g + 1]);
    pw[0][g][1] = cvtpk(s0[4*g + 2], s0[4*g + 3]);
    pw[1][g][0] = cvtpk(s1[4*g],     s1[4*g + 1]);
    pw[1][g][1] = cvtpk(s1[4*g + 2], s1[4*g + 3]);
  }
  #pragma unroll
  for (int m = 0; m < 2; ++m)
    #pragma unroll
    for (int kp = 0; kp < 2; ++kp)
      #pragma unroll
      for (int i = 0; i < 2; ++i)
        pl32swap(pw[m][2*kp][i], pw[m][2*kp + 1][i]);

  const char* Vc = (const char*)lsVt;
  const int swz = q5 & 7;
  __builtin_amdgcn_s_setprio(1);
  #pragma unroll
  for (int ks = 0; ks < 4; ++ks){
    const int m = ks >> 1, kp = ks & 1;
    union { unsigned u[4]; short8 s8; } pa;
    pa.u[0] = pw[m][2*kp][0];
    pa.u[1] = pw[m][2*kp][1];
    pa.u[2] = pw[m][2*kp + 1][0];
    pa.u[3] = pw[m][2*kp + 1][1];
    int c0 = ((2 * ks + hi) ^ swz) << 4;
    short8 v0 = *(const short8*)(Vc + q5 * 128 + c0);
    short8 v1 = *(const short8*)(Vc + (q5 + 32) * 128 + c0);
    accA = mfma32(pa.s8, v0, accA);
    accB = mfma32(pa.s8, v1, accB);
  }
  __builtin_amdgcn_s_setprio(0);
}

__global__ __launch_bounds__(256, 2) void attn_kernel(
    const u16* __restrict__ Q, const u16* __restrict__ K,
    const u16* __restrict__ Vt, u16* __restrict__ ctx)
{
  __shared__ __align__(16) u16 lsK[3][64*64];
  __shared__ __align__(16) u16 lsV[3][64*64];

  const int bid = blockIdx.x;
  const int xcd = bid & 7;
  const int j   = bid >> 3;            // 0..63
  const int bh  = xcd + 8 * (j >> 4);  // 4 bh per XCD
  const int st  = 15 - (j & 15);       // longest-first
  const int b = bh >> 4, h = bh & 15;
  const int tid = threadIdx.x;
  const int l = tid & 63, w = tid >> 6;
  const int q5 = l & 31, hi = l >> 5;
  const int qb   = st * 128 + w * 32;
  const int qgl  = qb + q5;
  const int nc   = (qb + 31) >> 6;     // wave's last compute tile
  const int tb   = 2 * st + 1;         // block's last kv tile (odd -> even iter count)

  const u16* Kb0 = &K[(size_t)(b * NS) * ND + h * 64];
  const u16* Vb0 = &Vt[(size_t)bh * 64 * NS];

  short8 qf[4];
  {
    const u16* Qrow = &Q[(size_t)(b * NS + qgl) * ND + h * 64 + hi * 8];
    #pragma unroll
    for (int ks = 0; ks < 4; ++ks)
      qf[ks] = *(const short8*)&Qrow[ks * 16];
  }

  float m_r = -3e38f, l_r = 0.f;
  f32x16 accA = {}, accB = {};
  f32x16 sA0, sA1, sB0, sB1;

  // prologue: stage tiles 0 and 1 (tb >= 1 always), compute QK(0)
  stage_tile(Kb0, ND, lsK[0], tid);
  stage_tile(Vb0, NS, lsV[0], tid);
  stage_tile(&Kb0[(size_t)64 * ND], ND, lsK[1], tid);
  stage_tile(&Vb0[64],              NS, lsV[1], tid);
  __syncthreads();
  qk_tile(lsK[0], qf, q5, hi, sA0, sA1);

  #pragma unroll 1
  for (int t = 0; t <= tb; t += 2){
    // ---- sub-iter A: current tile t (scores sA), produce sB = QK(t+1) ----
    {
      const int rs = (t + 2) % 3, rn = (t + 1) % 3, rc = t % 3;
      if (t + 2 <= tb){
        stage_tile(&Kb0[(size_t)(t + 2) * 64 * ND], ND, lsK[rs], tid);
        stage_tile(&Vb0[(t + 2) * 64],              NS, lsV[rs], tid);
      }
      if (t + 1 <= nc) qk_tile(lsK[rn], qf, q5, hi, sB0, sB1);
      if (t <= nc)     sm_pv(sA0, sA1, lsV[rc], t, qb, qgl, q5, hi, m_r, l_r, accA, accB);
      __syncthreads();
    }
    // ---- sub-iter B: current tile t+1 (scores sB), produce sA = QK(t+2) ----
    {
      const int t1 = t + 1;
      const int rs = (t1 + 2) % 3, rn = (t1 + 1) % 3, rc = t1 % 3;
      if (t1 + 2 <= tb){
        stage_tile(&Kb0[(size_t)(t1 + 2) * 64 * ND], ND, lsK[rs], tid);
        stage_tile(&Vb0[(t1 + 2) * 64],              NS, lsV[rs], tid);
      }
      if (t1 + 1 <= nc) qk_tile(lsK[rn], qf, q5, hi, sA0, sA1);
      if (t1 <= nc)     sm_pv(sB0, sB1, lsV[rc], t1, qb, qgl, q5, hi, m_r, l_r, accA, accB);
      __syncthreads();
    }
  }

  // epilogue
  float inv = RCP(l_r);
  #pragma unroll
  for (int r = 0; r < 16; ++r){
    int qrow = (r & 3) + 8 * (r >> 2) + 4 * hi;
    float iv = __shfl(inv, (l & 32) | qrow, 64);
    u16* crow = &ctx[(size_t)(b * NS + qb + qrow) * ND + h * 64 + q5];
    crow[0]  = f2bf(accA[r] * iv);
    crow[32] = f2bf(accB[r] * iv);
  }
}

extern "C" void kernel_launch(void* const* d_in, const int* in_sizes, int n_in,
                              void* d_out, int out_size, void* d_ws, size_t ws_size,
                              hipStream_t stream)
{
  const float* x  = (const float*)d_in[0];
  const float* Wq = (const float*)d_in[1];
  const float* Wk = (const float*)d_in[2];
  const float* Wv = (const float*)d_in[3];
  const float* Wo = (const float*)d_in[4];
  const float* bo = (const float*)d_in[5];
  float* out = (float*)d_out;
  char* ws = (char*)d_ws;

  u16* xb  = (u16*)(ws);
  u16* Wqb = (u16*)(ws + (8u  << 20));
  u16* Wkb = (u16*)(ws + (10u << 20));
  u16* Wvb = (u16*)(ws + (12u << 20));
  u16* Wob = (u16*)(ws + (14u << 20));
  u16* Qb  = (u16*)(ws + (16u << 20));
  u16* Kb  = (u16*)(ws + (24u << 20));
  u16* Vtb = (u16*)(ws + (32u << 20));
  u16* Cb  = (u16*)(ws + (40u << 20));

  cvt_kernel<<<4096, 256, 0, stream>>>(x, xb, NM * ND);
  cvt4_kernel<<<dim3(1024, 4), 256, 0, stream>>>(Wq, Wk, Wv, Wo, Wqb, Wkb, Wvb, Wob);

  gemm_qkv<<<dim3(32, 8, 3), 256, 0, stream>>>(xb, Wqb, Wkb, Wvb, Qb, Kb, Vtb);
  attn_kernel<<<512, 256, 0, stream>>>(Qb, Kb, Vtb, Cb);
  gemm_out<<<dim3(32, 8), 256, 0, stream>>>(Cb, Wob, bo, out);
}

// Round 8
// 133.428 us; speedup vs baseline: 3.0671x; 1.0024x over previous
//
#include <hip/hip_runtime.h>
#include <hip/hip_bf16.h>
#include <stdint.h>

typedef unsigned short u16;
typedef __attribute__((ext_vector_type(8))) short short8;
typedef __attribute__((ext_vector_type(4))) float f32x4;
typedef __attribute__((ext_vector_type(16))) float f32x16;
typedef __attribute__((ext_vector_type(4))) u16 u16x4;

#define NB 2
#define NS 2048
#define ND 1024
#define NH 16
#define NM 4096   // NB*NS

// 1/sqrt(1024) * log2(e): folded into Q so QK^T scores are base-2 scores
#define QSCALE 0.045084220f

// single-instruction exp2 (transcendental); avoid exp2f libcall
#if __has_builtin(__builtin_amdgcn_exp2f)
#define EXP2(x) __builtin_amdgcn_exp2f(x)
#else
__device__ __forceinline__ float __exp2_asm(float x){
  float r;
  asm("v_exp_f32 %0, %1" : "=v"(r) : "v"(x));
  return r;
}
#define EXP2(x) __exp2_asm(x)
#endif
#if __has_builtin(__builtin_amdgcn_rcpf)
#define RCP(x) __builtin_amdgcn_rcpf(x)
#else
#define RCP(x) (1.0f / (x))
#endif

// RNE f32 -> bf16
__device__ __forceinline__ u16 f2bf(float f){
  union { float f; unsigned u; } v; v.f = f;
  unsigned r = v.u + 0x7fff + ((v.u >> 16) & 1);
  return (u16)(r >> 16);
}

// packed f32 pair -> 2x bf16 in one u32 (hardware RNE); lo -> bits[15:0]
__device__ __forceinline__ unsigned cvtpk(float lo, float hi){
  unsigned r;
  asm("v_cvt_pk_bf16_f32 %0, %1, %2" : "=v"(r) : "v"(lo), "v"(hi));
  return r;
}

// v_permlane32_swap_b32: swap lane halves between the two operands
__device__ __forceinline__ void pl32swap(unsigned &e, unsigned &o){
  asm("v_permlane32_swap_b32 %0, %1" : "+v"(e), "+v"(o));
}

__device__ __forceinline__ void gload_lds16(const u16* g, u16* l){
  __builtin_amdgcn_global_load_lds(
      (const __attribute__((address_space(1))) unsigned int*)g,
      (__attribute__((address_space(3))) unsigned int*)l, 16, 0, 0);
}

__device__ __forceinline__ f32x16 mfma32(short8 a, short8 b, f32x16 c){
  return __builtin_amdgcn_mfma_f32_32x32x16_bf16(a, b, c, 0, 0, 0);
}

// ---------------- f32 -> bf16 convert ----------------
__global__ void cvt_kernel(const float* __restrict__ src, u16* __restrict__ dst, int n){
  int i = (blockIdx.x * blockDim.x + threadIdx.x) * 4;
  if (i < n){
    float4 v = *(const float4*)(src + i);
    u16x4 o = { f2bf(v.x), f2bf(v.y), f2bf(v.z), f2bf(v.w) };
    *(u16x4*)(dst + i) = o;
  }
}

__global__ void cvt4_kernel(const float* __restrict__ a, const float* __restrict__ b,
                            const float* __restrict__ c, const float* __restrict__ d,
                            u16* __restrict__ oa, u16* __restrict__ ob,
                            u16* __restrict__ oc, u16* __restrict__ od){
  const float* s; u16* o;
  switch (blockIdx.y){
    case 0: s = a; o = oa; break;
    case 1: s = b; o = ob; break;
    case 2: s = c; o = oc; break;
    default: s = d; o = od; break;
  }
  int i = (blockIdx.x * blockDim.x + threadIdx.x) * 4;
  float4 v = *(const float4*)(s + i);
  u16x4 pk = { f2bf(v.x), f2bf(v.y), f2bf(v.z), f2bf(v.w) };
  *(u16x4*)(o + i) = pk;
}

// ---------------- NT GEMM core ----------------
__device__ __forceinline__ void gemm_core(
    const u16* __restrict__ A, const u16* __restrict__ W,
    int m0, int n0, u16* lsA, u16* lsB, f32x4 acc[4][4])
{
  const int tid = threadIdx.x;
  const int l   = tid & 63;
  const int wr  = (tid >> 7) & 1;
  const int wc  = (tid >> 6) & 1;
  const int lr  = l & 15;
  const int lkb = (l >> 4) << 4;
  const int sr  = tid >> 3;
  const int scb = (tid & 7) << 4;

  for (int kt = 0; kt < 16; ++kt){
    const int k0 = kt << 6;
    #pragma unroll
    for (int i = 0; i < 4; ++i){
      int r   = (i << 5) + sr;
      int cbs = scb ^ ((r & 7) << 4);
      gload_lds16(&A[(size_t)(m0 + r) * ND + k0 + (cbs >> 1)], &lsA[r * 64 + (scb >> 1)]);
      gload_lds16(&W[(size_t)(n0 + r) * ND + k0 + (cbs >> 1)], &lsB[r * 64 + (scb >> 1)]);
    }
    __syncthreads();

    short8 af[4][2], bf[4][2];
    #pragma unroll
    for (int m16 = 0; m16 < 4; ++m16){
      int r  = (wr << 6) + (m16 << 4) + lr;
      int rx = (r & 7) << 4;
      #pragma unroll
      for (int ks = 0; ks < 2; ++ks){
        int off = r * 128 + (((ks << 6) + lkb) ^ rx);
        af[m16][ks] = *(const short8*)((const char*)lsA + off);
      }
    }
    #pragma unroll
    for (int n16 = 0; n16 < 4; ++n16){
      int r  = (wc << 6) + (n16 << 4) + lr;
      int rx = (r & 7) << 4;
      #pragma unroll
      for (int ks = 0; ks < 2; ++ks){
        int off = r * 128 + (((ks << 6) + lkb) ^ rx);
        bf[n16][ks] = *(const short8*)((const char*)lsB + off);
      }
    }
    #pragma unroll
    for (int m16 = 0; m16 < 4; ++m16)
      #pragma unroll
      for (int n16 = 0; n16 < 4; ++n16){
        acc[m16][n16] = __builtin_amdgcn_mfma_f32_16x16x32_bf16(af[m16][0], bf[n16][0], acc[m16][n16], 0, 0, 0);
        acc[m16][n16] = __builtin_amdgcn_mfma_f32_16x16x32_bf16(af[m16][1], bf[n16][1], acc[m16][n16], 0, 0, 0);
      }
    __syncthreads();
  }
}

// ---------------- fused QKV projection: grid (32, 8, 3) ----------------
__global__ __launch_bounds__(256) void gemm_qkv(
    const u16* __restrict__ xb,
    const u16* __restrict__ Wqb, const u16* __restrict__ Wkb, const u16* __restrict__ Wvb,
    u16* __restrict__ Qo, u16* __restrict__ Ko, u16* __restrict__ Vt)
{
  __shared__ u16 lsA[128*64];
  __shared__ u16 lsB[128*64];
  const int z = blockIdx.z;
  const u16* W = (z == 0) ? Wqb : (z == 1) ? Wkb : Wvb;
  const int m0 = blockIdx.x << 7, n0 = blockIdx.y << 7;
  f32x4 acc[4][4] = {};
  gemm_core(xb, W, m0, n0, lsA, lsB, acc);

  const int l  = threadIdx.x & 63;
  const int wr = (threadIdx.x >> 7) & 1, wc = (threadIdx.x >> 6) & 1;
  const int rb = m0 + (wr << 6) + ((l >> 4) << 2);
  const int cb = n0 + (wc << 6) + (l & 15);

  if (z < 2){
    const float sc = (z == 0) ? QSCALE : 1.0f;
    u16* C = (z == 0) ? Qo : Ko;
    #pragma unroll
    for (int m16 = 0; m16 < 4; ++m16)
      #pragma unroll
      for (int n16 = 0; n16 < 4; ++n16)
        #pragma unroll
        for (int r = 0; r < 4; ++r)
          C[(size_t)(rb + (m16 << 4) + r) * ND + cb + (n16 << 4)] = f2bf(acc[m16][n16][r] * sc);
  } else {
    #pragma unroll
    for (int m16 = 0; m16 < 4; ++m16){
      int srow = rb + (m16 << 4);
      int bi = srow >> 11, s = srow & 2047;
      #pragma unroll
      for (int n16 = 0; n16 < 4; ++n16){
        int col = cb + (n16 << 4);
        u16x4 pk = { f2bf(acc[m16][n16][0]), f2bf(acc[m16][n16][1]),
                     f2bf(acc[m16][n16][2]), f2bf(acc[m16][n16][3]) };
        *(u16x4*)&Vt[((size_t)(bi * 16 + (col >> 6)) * 64 + (col & 63)) * 2048 + s] = pk;
      }
    }
  }
}

// ---------------- output projection: grid (32, 8) ----------------
__global__ __launch_bounds__(256) void gemm_out(
    const u16* __restrict__ ctxb, const u16* __restrict__ Wob,
    const float* __restrict__ bo, float* __restrict__ out)
{
  __shared__ u16 lsA[128*64];
  __shared__ u16 lsB[128*64];
  const int m0 = blockIdx.x << 7, n0 = blockIdx.y << 7;
  f32x4 acc[4][4] = {};
  gemm_core(ctxb, Wob, m0, n0, lsA, lsB, acc);

  const int l  = threadIdx.x & 63;
  const int wr = (threadIdx.x >> 7) & 1, wc = (threadIdx.x >> 6) & 1;
  const int rb = m0 + (wr << 6) + ((l >> 4) << 2);
  const int cb = n0 + (wc << 6) + (l & 15);
  #pragma unroll
  for (int m16 = 0; m16 < 4; ++m16)
    #pragma unroll
    for (int n16 = 0; n16 < 4; ++n16)
      #pragma unroll
      for (int r = 0; r < 4; ++r){
        int col = cb + (n16 << 4);
        out[(size_t)(rb + (m16 << 4) + r) * ND + col] = acc[m16][n16][r] + bo[col];
      }
}

// ---------------- causal flash attention: counted-vmcnt 4-ring pipeline ----------------
// grid 512, XCD-pinned streams (K/V L2-resident). 4 waves x 32 q-rows per block.
// Ring depth 4; iter t: stage(t+3) | QK(t+1) | softmax+PV(t) | s_waitcnt vmcnt(4)
// + raw s_barrier. vmcnt(4) leaves stage(t+3)'s 4 loads IN FLIGHT across the
// barrier (T4) while guaranteeing stage(t+2) (read by next iter's QK) has landed.
// Tail iterations (no stage issued) drain with vmcnt(0).
__device__ __forceinline__ void stage_tile(const u16* src, int srcStride, u16* lds, int tid){
  const int rl = tid >> 3;
  const int ch = tid & 7;
  const int cs = ch ^ (rl & 7);
  gload_lds16(&src[(size_t)rl * srcStride + cs * 8],        &lds[rl * 64 + ch * 8]);
  gload_lds16(&src[(size_t)(rl + 32) * srcStride + cs * 8], &lds[(rl + 32) * 64 + ch * 8]);
}

// QK^T MFMA cluster: raw base-2 scores of one 64-kv tile into (s0, s1)
__device__ __forceinline__ void qk_tile(const u16* lsKt, const short8 qf[4],
                                        int q5, int hi, f32x16 &s0, f32x16 &s1){
  const char* Kc = (const char*)lsKt;
  const int swz = q5 & 7;
  f32x16 a = {}, b = {};
  __builtin_amdgcn_s_setprio(1);
  #pragma unroll
  for (int ks = 0; ks < 4; ++ks){
    int c0 = ((2 * ks + hi) ^ swz) << 4;
    short8 k0 = *(const short8*)(Kc + q5 * 128 + c0);
    short8 k1 = *(const short8*)(Kc + (q5 + 32) * 128 + c0);
    a = mfma32(k0, qf[ks], a);
    b = mfma32(k1, qf[ks], b);
  }
  __builtin_amdgcn_s_setprio(0);
  s0 = a; s1 = b;
}

// softmax (online, base-2, defer-max THR=8) + pack + PV MFMA cluster
__device__ __forceinline__ void sm_pv(f32x16 s0, f32x16 s1, const u16* lsVt,
                                      int t, int qb, int qgl, int q5, int hi,
                                      float &m_r, float &l_r, f32x16 &accA, f32x16 &accB){
  // causal mask (only tiles crossing this wave's diagonal)
  if (t * 64 + 63 > qb){
    #pragma unroll
    for (int r = 0; r < 16; ++r){
      int kl = t * 64 + (r & 3) + 8 * (r >> 2) + 4 * hi;
      if (kl > qgl)      s0[r] = -3e38f;
      if (kl + 32 > qgl) s1[r] = -3e38f;
    }
  }
  // row max: in-lane tree + hi-swap
  float mx[16];
  #pragma unroll
  for (int r = 0; r < 16; ++r) mx[r] = fmaxf(s0[r], s1[r]);
  #pragma unroll
  for (int stp = 8; stp > 0; stp >>= 1)
    #pragma unroll
    for (int r = 0; r < stp; ++r) mx[r] = fmaxf(mx[r], mx[r + stp]);
  float pm = fmaxf(mx[0], __shfl_xor(mx[0], 32));

  if (__any(pm > m_r + 8.f)){
    float mn = fmaxf(m_r, pm);
    float e  = EXP2(m_r - mn);
    m_r = mn; l_r *= e;
    #pragma unroll
    for (int r = 0; r < 16; ++r){ accA[r] *= e; accB[r] *= e; }
  }

  #pragma unroll
  for (int r = 0; r < 16; ++r){
    s0[r] = EXP2(s0[r] - m_r);
    s1[r] = EXP2(s1[r] - m_r);
  }
  float sm[16];
  #pragma unroll
  for (int r = 0; r < 16; ++r) sm[r] = s0[r] + s1[r];
  #pragma unroll
  for (int stp = 8; stp > 0; stp >>= 1)
    #pragma unroll
    for (int r = 0; r < stp; ++r) sm[r] += sm[r + stp];
  l_r += sm[0] + __shfl_xor(sm[0], 32);

  // pack P -> bf16; permlane32_swap assembles A-fragments
  unsigned pw[2][4][2];
  #pragma unroll
  for (int g = 0; g < 4; ++g){
    pw[0][g][0] = cvtpk(s0[4*g],     s0[4*g + 1]);
    pw[0][g][1] = cvtpk(s0[4*g + 2], s0[4*g + 3]);
    pw[1][g][0] = cvtpk(s1[4*g],     s1[4*g + 1]);
    pw[1][g][1] = cvtpk(s1[4*g + 2], s1[4*g + 3]);
  }
  #pragma unroll
  for (int m = 0; m < 2; ++m)
    #pragma unroll
    for (int kp = 0; kp < 2; ++kp)
      #pragma unroll
      for (int i = 0; i < 2; ++i)
        pl32swap(pw[m][2*kp][i], pw[m][2*kp + 1][i]);

  const char* Vc = (const char*)lsVt;
  const int swz = q5 & 7;
  __builtin_amdgcn_s_setprio(1);
  #pragma unroll
  for (int ks = 0; ks < 4; ++ks){
    const int m = ks >> 1, kp = ks & 1;
    union { unsigned u[4]; short8 s8; } pa;
    pa.u[0] = pw[m][2*kp][0];
    pa.u[1] = pw[m][2*kp][1];
    pa.u[2] = pw[m][2*kp + 1][0];
    pa.u[3] = pw[m][2*kp + 1][1];
    int c0 = ((2 * ks + hi) ^ swz) << 4;
    short8 v0 = *(const short8*)(Vc + q5 * 128 + c0);
    short8 v1 = *(const short8*)(Vc + (q5 + 32) * 128 + c0);
    accA = mfma32(pa.s8, v0, accA);
    accB = mfma32(pa.s8, v1, accB);
  }
  __builtin_amdgcn_s_setprio(0);
}

// one pipeline sub-iteration (tile T consumed, tile T+1's scores produced)
#define SUBITER(T, SC0, SC1, SN0, SN1)                                            \
  {                                                                               \
    const int t_ = (T);                                                           \
    if (t_ + 3 <= tb){                                                            \
      stage_tile(&Kb0[(size_t)(t_ + 3) * 64 * ND], ND, lsK[(t_ + 3) & 3], tid);   \
      stage_tile(&Vb0[(t_ + 3) * 64],              NS, lsV[(t_ + 3) & 3], tid);   \
    }                                                                             \
    if (t_ + 1 <= nc) qk_tile(lsK[(t_ + 1) & 3], qf, q5, hi, SN0, SN1);           \
    if (t_ <= nc)     sm_pv(SC0, SC1, lsV[t_ & 3], t_, qb, qgl, q5, hi,           \
                            m_r, l_r, accA, accB);                                \
    if (t_ + 3 <= tb) asm volatile("s_waitcnt vmcnt(4)" ::: "memory");            \
    else              asm volatile("s_waitcnt vmcnt(0)" ::: "memory");            \
    __builtin_amdgcn_sched_barrier(0);                                            \
    __builtin_amdgcn_s_barrier();                                                 \
    __builtin_amdgcn_sched_barrier(0);                                            \
  }

__global__ __launch_bounds__(256, 2) void attn_kernel(
    const u16* __restrict__ Q, const u16* __restrict__ K,
    const u16* __restrict__ Vt, u16* __restrict__ ctx)
{
  __shared__ __align__(16) u16 lsK[4][64*64];
  __shared__ __align__(16) u16 lsV[4][64*64];

  const int bid = blockIdx.x;
  const int xcd = bid & 7;
  const int j   = bid >> 3;            // 0..63
  const int bh  = xcd + 8 * (j >> 4);  // 4 bh per XCD
  const int st  = 15 - (j & 15);       // longest-first
  const int b = bh >> 4, h = bh & 15;
  const int tid = threadIdx.x;
  const int l = tid & 63, w = tid >> 6;
  const int q5 = l & 31, hi = l >> 5;
  const int qb   = st * 128 + w * 32;
  const int qgl  = qb + q5;
  const int nc   = (qb + 31) >> 6;     // wave's last compute tile
  const int tb   = 2 * st + 1;         // block's last kv tile (odd -> even iter count)

  const u16* Kb0 = &K[(size_t)(b * NS) * ND + h * 64];
  const u16* Vb0 = &Vt[(size_t)bh * 64 * NS];

  short8 qf[4];
  {
    const u16* Qrow = &Q[(size_t)(b * NS + qgl) * ND + h * 64 + hi * 8];
    #pragma unroll
    for (int ks = 0; ks < 4; ++ks)
      qf[ks] = *(const short8*)&Qrow[ks * 16];
  }

  float m_r = -3e38f, l_r = 0.f;
  f32x16 accA = {}, accB = {};
  f32x16 sA0, sA1, sB0, sB1;

  // prologue: stage tiles 0,1 (always exist) and 2 (if present);
  // vmcnt(4) leaves only stage(2) in flight -> tiles 0,1 landed.
  stage_tile(Kb0, ND, lsK[0], tid);
  stage_tile(Vb0, NS, lsV[0], tid);
  stage_tile(&Kb0[(size_t)64 * ND], ND, lsK[1], tid);
  stage_tile(&Vb0[64],              NS, lsV[1], tid);
  if (2 <= tb){
    stage_tile(&Kb0[(size_t)128 * ND], ND, lsK[2], tid);
    stage_tile(&Vb0[128],              NS, lsV[2], tid);
    asm volatile("s_waitcnt vmcnt(4)" ::: "memory");
  } else {
    asm volatile("s_waitcnt vmcnt(0)" ::: "memory");
  }
  __builtin_amdgcn_sched_barrier(0);
  __builtin_amdgcn_s_barrier();
  __builtin_amdgcn_sched_barrier(0);
  qk_tile(lsK[0], qf, q5, hi, sA0, sA1);

  #pragma unroll 1
  for (int t = 0; t <= tb; t += 2){
    SUBITER(t,     sA0, sA1, sB0, sB1);
    SUBITER(t + 1, sB0, sB1, sA0, sA1);
  }

  // epilogue
  float inv = RCP(l_r);
  #pragma unroll
  for (int r = 0; r < 16; ++r){
    int qrow = (r & 3) + 8 * (r >> 2) + 4 * hi;
    float iv = __shfl(inv, (l & 32) | qrow, 64);
    u16* crow = &ctx[(size_t)(b * NS + qb + qrow) * ND + h * 64 + q5];
    crow[0]  = f2bf(accA[r] * iv);
    crow[32] = f2bf(accB[r] * iv);
  }
}

extern "C" void kernel_launch(void* const* d_in, const int* in_sizes, int n_in,
                              void* d_out, int out_size, void* d_ws, size_t ws_size,
                              hipStream_t stream)
{
  const float* x  = (const float*)d_in[0];
  const float* Wq = (const float*)d_in[1];
  const float* Wk = (const float*)d_in[2];
  const float* Wv = (const float*)d_in[3];
  const float* Wo = (const float*)d_in[4];
  const float* bo = (const float*)d_in[5];
  float* out = (float*)d_out;
  char* ws = (char*)d_ws;

  u16* xb  = (u16*)(ws);
  u16* Wqb = (u16*)(ws + (8u  << 20));
  u16* Wkb = (u16*)(ws + (10u << 20));
  u16* Wvb = (u16*)(ws + (12u << 20));
  u16* Wob = (u16*)(ws + (14u << 20));
  u16* Qb  = (u16*)(ws + (16u << 20));
  u16* Kb  = (u16*)(ws + (24u << 20));
  u16* Vtb = (u16*)(ws + (32u << 20));
  u16* Cb  = (u16*)(ws + (40u << 20));

  cvt_kernel<<<4096, 256, 0, stream>>>(x, xb, NM * ND);
  cvt4_kernel<<<dim3(1024, 4), 256, 0, stream>>>(Wq, Wk, Wv, Wo, Wqb, Wkb, Wvb, Wob);

  gemm_qkv<<<dim3(32, 8, 3), 256, 0, stream>>>(xb, Wqb, Wkb, Wvb, Qb, Kb, Vtb);
  attn_kernel<<<512, 256, 0, stream>>>(Qb, Kb, Vtb, Cb);
  gemm_out<<<dim3(32, 8), 256, 0, stream>>>(Cb, Wob, bo, out);
}

// Round 10
// 125.465 us; speedup vs baseline: 3.2618x; 1.0635x over previous
//
#include <hip/hip_runtime.h>
#include <hip/hip_bf16.h>
#include <stdint.h>

typedef unsigned short u16;
typedef __attribute__((ext_vector_type(8))) short short8;
typedef __attribute__((ext_vector_type(4))) float f32x4;
typedef __attribute__((ext_vector_type(16))) float f32x16;
typedef __attribute__((ext_vector_type(4))) u16 u16x4;

#define NB 2
#define NS 2048
#define ND 1024
#define NH 16
#define NM 4096   // NB*NS

// 1/sqrt(1024) * log2(e): folded into Q so QK^T scores are base-2 scores
#define QSCALE 0.045084220f

// single-instruction exp2 (transcendental); avoid exp2f libcall
#if __has_builtin(__builtin_amdgcn_exp2f)
#define EXP2(x) __builtin_amdgcn_exp2f(x)
#else
__device__ __forceinline__ float __exp2_asm(float x){
  float r;
  asm("v_exp_f32 %0, %1" : "=v"(r) : "v"(x));
  return r;
}
#define EXP2(x) __exp2_asm(x)
#endif
#if __has_builtin(__builtin_amdgcn_rcpf)
#define RCP(x) __builtin_amdgcn_rcpf(x)
#else
#define RCP(x) (1.0f / (x))
#endif

// RNE f32 -> bf16
__device__ __forceinline__ u16 f2bf(float f){
  union { float f; unsigned u; } v; v.f = f;
  unsigned r = v.u + 0x7fff + ((v.u >> 16) & 1);
  return (u16)(r >> 16);
}

// packed f32 pair -> 2x bf16 in one u32 (hardware RNE); lo -> bits[15:0]
__device__ __forceinline__ unsigned cvtpk(float lo, float hi){
  unsigned r;
  asm("v_cvt_pk_bf16_f32 %0, %1, %2" : "=v"(r) : "v"(lo), "v"(hi));
  return r;
}

// v_permlane32_swap_b32: swap lane halves between the two operands
__device__ __forceinline__ void pl32swap(unsigned &e, unsigned &o){
  asm("v_permlane32_swap_b32 %0, %1" : "+v"(e), "+v"(o));
}

__device__ __forceinline__ void gload_lds16(const u16* g, u16* l){
  __builtin_amdgcn_global_load_lds(
      (const __attribute__((address_space(1))) unsigned int*)g,
      (__attribute__((address_space(3))) unsigned int*)l, 16, 0, 0);
}

__device__ __forceinline__ f32x16 mfma32(short8 a, short8 b, f32x16 c){
  return __builtin_amdgcn_mfma_f32_32x32x16_bf16(a, b, c, 0, 0, 0);
}

// ---------------- f32 -> bf16 convert ----------------
__global__ void cvt_kernel(const float* __restrict__ src, u16* __restrict__ dst, int n){
  int i = (blockIdx.x * blockDim.x + threadIdx.x) * 4;
  if (i < n){
    float4 v = *(const float4*)(src + i);
    u16x4 o = { f2bf(v.x), f2bf(v.y), f2bf(v.z), f2bf(v.w) };
    *(u16x4*)(dst + i) = o;
  }
}

__global__ void cvt4_kernel(const float* __restrict__ a, const float* __restrict__ b,
                            const float* __restrict__ c, const float* __restrict__ d,
                            u16* __restrict__ oa, u16* __restrict__ ob,
                            u16* __restrict__ oc, u16* __restrict__ od){
  const float* s; u16* o;
  switch (blockIdx.y){
    case 0: s = a; o = oa; break;
    case 1: s = b; o = ob; break;
    case 2: s = c; o = oc; break;
    default: s = d; o = od; break;
  }
  int i = (blockIdx.x * blockDim.x + threadIdx.x) * 4;
  float4 v = *(const float4*)(s + i);
  u16x4 pk = { f2bf(v.x), f2bf(v.y), f2bf(v.z), f2bf(v.w) };
  *(u16x4*)(o + i) = pk;
}

// ---------------- NT GEMM core ----------------
__device__ __forceinline__ void gemm_core(
    const u16* __restrict__ A, const u16* __restrict__ W,
    int m0, int n0, u16* lsA, u16* lsB, f32x4 acc[4][4])
{
  const int tid = threadIdx.x;
  const int l   = tid & 63;
  const int wr  = (tid >> 7) & 1;
  const int wc  = (tid >> 6) & 1;
  const int lr  = l & 15;
  const int lkb = (l >> 4) << 4;
  const int sr  = tid >> 3;
  const int scb = (tid & 7) << 4;

  for (int kt = 0; kt < 16; ++kt){
    const int k0 = kt << 6;
    #pragma unroll
    for (int i = 0; i < 4; ++i){
      int r   = (i << 5) + sr;
      int cbs = scb ^ ((r & 7) << 4);
      gload_lds16(&A[(size_t)(m0 + r) * ND + k0 + (cbs >> 1)], &lsA[r * 64 + (scb >> 1)]);
      gload_lds16(&W[(size_t)(n0 + r) * ND + k0 + (cbs >> 1)], &lsB[r * 64 + (scb >> 1)]);
    }
    __syncthreads();

    short8 af[4][2], bf[4][2];
    #pragma unroll
    for (int m16 = 0; m16 < 4; ++m16){
      int r  = (wr << 6) + (m16 << 4) + lr;
      int rx = (r & 7) << 4;
      #pragma unroll
      for (int ks = 0; ks < 2; ++ks){
        int off = r * 128 + (((ks << 6) + lkb) ^ rx);
        af[m16][ks] = *(const short8*)((const char*)lsA + off);
      }
    }
    #pragma unroll
    for (int n16 = 0; n16 < 4; ++n16){
      int r  = (wc << 6) + (n16 << 4) + lr;
      int rx = (r & 7) << 4;
      #pragma unroll
      for (int ks = 0; ks < 2; ++ks){
        int off = r * 128 + (((ks << 6) + lkb) ^ rx);
        bf[n16][ks] = *(const short8*)((const char*)lsB + off);
      }
    }
    #pragma unroll
    for (int m16 = 0; m16 < 4; ++m16)
      #pragma unroll
      for (int n16 = 0; n16 < 4; ++n16){
        acc[m16][n16] = __builtin_amdgcn_mfma_f32_16x16x32_bf16(af[m16][0], bf[n16][0], acc[m16][n16], 0, 0, 0);
        acc[m16][n16] = __builtin_amdgcn_mfma_f32_16x16x32_bf16(af[m16][1], bf[n16][1], acc[m16][n16], 0, 0, 0);
      }
    __syncthreads();
  }
}

// ---------------- fused QKV projection: grid (32, 8, 3) ----------------
__global__ __launch_bounds__(256) void gemm_qkv(
    const u16* __restrict__ xb,
    const u16* __restrict__ Wqb, const u16* __restrict__ Wkb, const u16* __restrict__ Wvb,
    u16* __restrict__ Qo, u16* __restrict__ Ko, u16* __restrict__ Vt)
{
  __shared__ u16 lsA[128*64];
  __shared__ u16 lsB[128*64];
  const int z = blockIdx.z;
  const u16* W = (z == 0) ? Wqb : (z == 1) ? Wkb : Wvb;
  const int m0 = blockIdx.x << 7, n0 = blockIdx.y << 7;
  f32x4 acc[4][4] = {};
  gemm_core(xb, W, m0, n0, lsA, lsB, acc);

  const int l  = threadIdx.x & 63;
  const int wr = (threadIdx.x >> 7) & 1, wc = (threadIdx.x >> 6) & 1;
  const int rb = m0 + (wr << 6) + ((l >> 4) << 2);
  const int cb = n0 + (wc << 6) + (l & 15);

  if (z < 2){
    const float sc = (z == 0) ? QSCALE : 1.0f;
    u16* C = (z == 0) ? Qo : Ko;
    #pragma unroll
    for (int m16 = 0; m16 < 4; ++m16)
      #pragma unroll
      for (int n16 = 0; n16 < 4; ++n16)
        #pragma unroll
        for (int r = 0; r < 4; ++r)
          C[(size_t)(rb + (m16 << 4) + r) * ND + cb + (n16 << 4)] = f2bf(acc[m16][n16][r] * sc);
  } else {
    #pragma unroll
    for (int m16 = 0; m16 < 4; ++m16){
      int srow = rb + (m16 << 4);
      int bi = srow >> 11, s = srow & 2047;
      #pragma unroll
      for (int n16 = 0; n16 < 4; ++n16){
        int col = cb + (n16 << 4);
        u16x4 pk = { f2bf(acc[m16][n16][0]), f2bf(acc[m16][n16][1]),
                     f2bf(acc[m16][n16][2]), f2bf(acc[m16][n16][3]) };
        *(u16x4*)&Vt[((size_t)(bi * 16 + (col >> 6)) * 64 + (col & 63)) * 2048 + s] = pk;
      }
    }
  }
}

// ---------------- output projection: grid (32, 8) ----------------
__global__ __launch_bounds__(256) void gemm_out(
    const u16* __restrict__ ctxb, const u16* __restrict__ Wob,
    const float* __restrict__ bo, float* __restrict__ out)
{
  __shared__ u16 lsA[128*64];
  __shared__ u16 lsB[128*64];
  const int m0 = blockIdx.x << 7, n0 = blockIdx.y << 7;
  f32x4 acc[4][4] = {};
  gemm_core(ctxb, Wob, m0, n0, lsA, lsB, acc);

  const int l  = threadIdx.x & 63;
  const int wr = (threadIdx.x >> 7) & 1, wc = (threadIdx.x >> 6) & 1;
  const int rb = m0 + (wr << 6) + ((l >> 4) << 2);
  const int cb = n0 + (wc << 6) + (l & 15);
  #pragma unroll
  for (int m16 = 0; m16 < 4; ++m16)
    #pragma unroll
    for (int n16 = 0; n16 < 4; ++n16)
      #pragma unroll
      for (int r = 0; r < 4; ++r){
        int col = cb + (n16 << 4);
        out[(size_t)(rb + (m16 << 4) + r) * ND + col] = acc[m16][n16][r] + bo[col];
      }
}

// ---------------- causal flash attention: balanced-pair 4-ring pipeline ----------------
// grid 512 = exactly 2 blocks/CU. Within an XCD the scheduler wrap-pairs local
// blocks j and j+32 on one CU, so st is assigned ANTI-CORRELATED across the wrap:
//   stream=(j&31)>>3, idx=j&7, st = (j<32) ? 15-idx : idx, bh = xcd + 8*stream.
// Wrap partners share the stream (L2 locality) and their kv-iters sum to 34 for
// EVERY CU (was 4..64 -> critical-path CU halves). Each (bh,st) covered once.
__device__ __forceinline__ void stage_tile(const u16* src, int srcStride, u16* lds, int tid){
  const int rl = tid >> 3;
  const int ch = tid & 7;
  const int cs = ch ^ (rl & 7);
  gload_lds16(&src[(size_t)rl * srcStride + cs * 8],        &lds[rl * 64 + ch * 8]);
  gload_lds16(&src[(size_t)(rl + 32) * srcStride + cs * 8], &lds[(rl + 32) * 64 + ch * 8]);
}

// QK^T MFMA cluster: raw base-2 scores of one 64-kv tile into (s0, s1)
__device__ __forceinline__ void qk_tile(const u16* lsKt, const short8 qf[4],
                                        int q5, int hi, f32x16 &s0, f32x16 &s1){
  const char* Kc = (const char*)lsKt;
  const int swz = q5 & 7;
  f32x16 a = {}, b = {};
  __builtin_amdgcn_s_setprio(1);
  #pragma unroll
  for (int ks = 0; ks < 4; ++ks){
    int c0 = ((2 * ks + hi) ^ swz) << 4;
    short8 k0 = *(const short8*)(Kc + q5 * 128 + c0);
    short8 k1 = *(const short8*)(Kc + (q5 + 32) * 128 + c0);
    a = mfma32(k0, qf[ks], a);
    b = mfma32(k1, qf[ks], b);
  }
  __builtin_amdgcn_s_setprio(0);
  s0 = a; s1 = b;
}

// softmax (online, base-2, defer-max THR=8) + pack + PV MFMA cluster
__device__ __forceinline__ void sm_pv(f32x16 s0, f32x16 s1, const u16* lsVt,
                                      int t, int qb, int qgl, int q5, int hi,
                                      float &m_r, float &l_r, f32x16 &accA, f32x16 &accB){
  // causal mask (only tiles crossing this wave's diagonal)
  if (t * 64 + 63 > qb){
    #pragma unroll
    for (int r = 0; r < 16; ++r){
      int kl = t * 64 + (r & 3) + 8 * (r >> 2) + 4 * hi;
      if (kl > qgl)      s0[r] = -3e38f;
      if (kl + 32 > qgl) s1[r] = -3e38f;
    }
  }
  // row max: in-lane tree + hi-swap
  float mx[16];
  #pragma unroll
  for (int r = 0; r < 16; ++r) mx[r] = fmaxf(s0[r], s1[r]);
  #pragma unroll
  for (int stp = 8; stp > 0; stp >>= 1)
    #pragma unroll
    for (int r = 0; r < stp; ++r) mx[r] = fmaxf(mx[r], mx[r + stp]);
  float pm = fmaxf(mx[0], __shfl_xor(mx[0], 32));

  if (__any(pm > m_r + 8.f)){
    float mn = fmaxf(m_r, pm);
    float e  = EXP2(m_r - mn);
    m_r = mn; l_r *= e;
    #pragma unroll
    for (int r = 0; r < 16; ++r){ accA[r] *= e; accB[r] *= e; }
  }

  #pragma unroll
  for (int r = 0; r < 16; ++r){
    s0[r] = EXP2(s0[r] - m_r);
    s1[r] = EXP2(s1[r] - m_r);
  }
  float sm[16];
  #pragma unroll
  for (int r = 0; r < 16; ++r) sm[r] = s0[r] + s1[r];
  #pragma unroll
  for (int stp = 8; stp > 0; stp >>= 1)
    #pragma unroll
    for (int r = 0; r < stp; ++r) sm[r] += sm[r + stp];
  l_r += sm[0] + __shfl_xor(sm[0], 32);

  // pack P -> bf16; permlane32_swap assembles A-fragments
  unsigned pw[2][4][2];
  #pragma unroll
  for (int g = 0; g < 4; ++g){
    pw[0][g][0] = cvtpk(s0[4*g],     s0[4*g + 1]);
    pw[0][g][1] = cvtpk(s0[4*g + 2], s0[4*g + 3]);
    pw[1][g][0] = cvtpk(s1[4*g],     s1[4*g + 1]);
    pw[1][g][1] = cvtpk(s1[4*g + 2], s1[4*g + 3]);
  }
  #pragma unroll
  for (int m = 0; m < 2; ++m)
    #pragma unroll
    for (int kp = 0; kp < 2; ++kp)
      #pragma unroll
      for (int i = 0; i < 2; ++i)
        pl32swap(pw[m][2*kp][i], pw[m][2*kp + 1][i]);

  const char* Vc = (const char*)lsVt;
  const int swz = q5 & 7;
  __builtin_amdgcn_s_setprio(1);
  #pragma unroll
  for (int ks = 0; ks < 4; ++ks){
    const int m = ks >> 1, kp = ks & 1;
    union { unsigned u[4]; short8 s8; } pa;
    pa.u[0] = pw[m][2*kp][0];
    pa.u[1] = pw[m][2*kp][1];
    pa.u[2] = pw[m][2*kp + 1][0];
    pa.u[3] = pw[m][2*kp + 1][1];
    int c0 = ((2 * ks + hi) ^ swz) << 4;
    short8 v0 = *(const short8*)(Vc + q5 * 128 + c0);
    short8 v1 = *(const short8*)(Vc + (q5 + 32) * 128 + c0);
    accA = mfma32(pa.s8, v0, accA);
    accB = mfma32(pa.s8, v1, accB);
  }
  __builtin_amdgcn_s_setprio(0);
}

// one pipeline sub-iteration (tile T consumed, tile T+1's scores produced)
#define SUBITER(T, SC0, SC1, SN0, SN1)                                            \
  {                                                                               \
    const int t_ = (T);                                                           \
    if (t_ + 3 <= tb){                                                            \
      stage_tile(&Kb0[(size_t)(t_ + 3) * 64 * ND], ND, lsK[(t_ + 3) & 3], tid);   \
      stage_tile(&Vb0[(t_ + 3) * 64],              NS, lsV[(t_ + 3) & 3], tid);   \
    }                                                                             \
    if (t_ + 1 <= nc) qk_tile(lsK[(t_ + 1) & 3], qf, q5, hi, SN0, SN1);           \
    if (t_ <= nc)     sm_pv(SC0, SC1, lsV[t_ & 3], t_, qb, qgl, q5, hi,           \
                            m_r, l_r, accA, accB);                                \
    if (t_ + 3 <= tb) asm volatile("s_waitcnt vmcnt(4)" ::: "memory");            \
    else              asm volatile("s_waitcnt vmcnt(0)" ::: "memory");            \
    __builtin_amdgcn_sched_barrier(0);                                            \
    __builtin_amdgcn_s_barrier();                                                 \
    __builtin_amdgcn_sched_barrier(0);                                            \
  }

__global__ __launch_bounds__(256, 2) void attn_kernel(
    const u16* __restrict__ Q, const u16* __restrict__ K,
    const u16* __restrict__ Vt, u16* __restrict__ ctx)
{
  __shared__ __align__(16) u16 lsK[4][64*64];
  __shared__ __align__(16) u16 lsV[4][64*64];

  const int bid = blockIdx.x;
  const int xcd = bid & 7;
  const int j   = bid >> 3;              // 0..63 local to XCD
  const int strm = (j & 31) >> 3;        // 0..3 bh-stream on this XCD
  const int idx  = j & 7;
  const int st   = (j < 32) ? (15 - idx) : idx;   // wrap partners sum to 15
  const int bh   = xcd + 8 * strm;
  const int b = bh >> 4, h = bh & 15;
  const int tid = threadIdx.x;
  const int l = tid & 63, w = tid >> 6;
  const int q5 = l & 31, hi = l >> 5;
  const int qb   = st * 128 + w * 32;
  const int qgl  = qb + q5;
  const int nc   = (qb + 31) >> 6;     // wave's last compute tile
  const int tb   = 2 * st + 1;         // block's last kv tile (odd -> even iter count)

  const u16* Kb0 = &K[(size_t)(b * NS) * ND + h * 64];
  const u16* Vb0 = &Vt[(size_t)bh * 64 * NS];

  short8 qf[4];
  {
    const u16* Qrow = &Q[(size_t)(b * NS + qgl) * ND + h * 64 + hi * 8];
    #pragma unroll
    for (int ks = 0; ks < 4; ++ks)
      qf[ks] = *(const short8*)&Qrow[ks * 16];
  }

  float m_r = -3e38f, l_r = 0.f;
  f32x16 accA = {}, accB = {};
  f32x16 sA0, sA1, sB0, sB1;

  // prologue: stage tiles 0,1 (always exist) and 2 (if present);
  // vmcnt(4) leaves only stage(2) in flight -> tiles 0,1 landed.
  stage_tile(Kb0, ND, lsK[0], tid);
  stage_tile(Vb0, NS, lsV[0], tid);
  stage_tile(&Kb0[(size_t)64 * ND], ND, lsK[1], tid);
  stage_tile(&Vb0[64],              NS, lsV[1], tid);
  if (2 <= tb){
    stage_tile(&Kb0[(size_t)128 * ND], ND, lsK[2], tid);
    stage_tile(&Vb0[128],              NS, lsV[2], tid);
    asm volatile("s_waitcnt vmcnt(4)" ::: "memory");
  } else {
    asm volatile("s_waitcnt vmcnt(0)" ::: "memory");
  }
  __builtin_amdgcn_sched_barrier(0);
  __builtin_amdgcn_s_barrier();
  __builtin_amdgcn_sched_barrier(0);
  qk_tile(lsK[0], qf, q5, hi, sA0, sA1);

  #pragma unroll 1
  for (int t = 0; t <= tb; t += 2){
    SUBITER(t,     sA0, sA1, sB0, sB1);
    SUBITER(t + 1, sB0, sB1, sA0, sA1);
  }

  // epilogue
  float inv = RCP(l_r);
  #pragma unroll
  for (int r = 0; r < 16; ++r){
    int qrow = (r & 3) + 8 * (r >> 2) + 4 * hi;
    float iv = __shfl(inv, (l & 32) | qrow, 64);
    u16* crow = &ctx[(size_t)(b * NS + qb + qrow) * ND + h * 64 + q5];
    crow[0]  = f2bf(accA[r] * iv);
    crow[32] = f2bf(accB[r] * iv);
  }
}

extern "C" void kernel_launch(void* const* d_in, const int* in_sizes, int n_in,
                              void* d_out, int out_size, void* d_ws, size_t ws_size,
                              hipStream_t stream)
{
  const float* x  = (const float*)d_in[0];
  const float* Wq = (const float*)d_in[1];
  const float* Wk = (const float*)d_in[2];
  const float* Wv = (const float*)d_in[3];
  const float* Wo = (const float*)d_in[4];
  const float* bo = (const float*)d_in[5];
  float* out = (float*)d_out;
  char* ws = (char*)d_ws;

  u16* xb  = (u16*)(ws);
  u16* Wqb = (u16*)(ws + (8u  << 20));
  u16* Wkb = (u16*)(ws + (10u << 20));
  u16* Wvb = (u16*)(ws + (12u << 20));
  u16* Wob = (u16*)(ws + (14u << 20));
  u16* Qb  = (u16*)(ws + (16u << 20));
  u16* Kb  = (u16*)(ws + (24u << 20));
  u16* Vtb = (u16*)(ws + (32u << 20));
  u16* Cb  = (u16*)(ws + (40u << 20));

  cvt_kernel<<<4096, 256, 0, stream>>>(x, xb, NM * ND);
  cvt4_kernel<<<dim3(1024, 4), 256, 0, stream>>>(Wq, Wk, Wv, Wo, Wqb, Wkb, Wvb, Wob);

  gemm_qkv<<<dim3(32, 8, 3), 256, 0, stream>>>(xb, Wqb, Wkb, Wvb, Qb, Kb, Vtb);
  attn_kernel<<<512, 256, 0, stream>>>(Qb, Kb, Vtb, Cb);
  gemm_out<<<dim3(32, 8), 256, 0, stream>>>(Cb, Wob, bo, out);
}